// Round 2
// baseline (3219.838 us; speedup 1.0000x reference)
//
#include <hip/hip_runtime.h>
#include <hip/hip_bf16.h>
#include <math.h>

typedef __bf16 bf16_t;
typedef __bf16 bf16x8 __attribute__((ext_vector_type(8)));
typedef float  f32x4  __attribute__((ext_vector_type(4)));

#define TOKENS 8192
#define DIMV   768
#define INNERV 768
#define QKVW   2304
#define MLPW   3072
#define NSEQ   1024
#define NB     8
#define NH     12
#define DH     64

enum { EP_STORE = 0, EP_BIAS_RES = 1, EP_BIAS_GELU = 2 };

// async global->LDS DMA, 16B per lane. LDS dest must be wave-uniform base + lane*16
// (our staging layout is exactly linear in lane order, so this holds).
__device__ __forceinline__ void gload_lds16(const bf16_t* g, bf16_t* l)
{
  __builtin_amdgcn_global_load_lds((const __attribute__((address_space(1))) void*)g,
                                   (__attribute__((address_space(3))) void*)l,
                                   16, 0, 0);
}

// ---------------- GEMM: C[M,N] = s * (A[M,K] * B[N,K]^T) + bias, bf16 in, f32 acc ----
// 128x128 tile, BK=32, double-buffered LDS with prefetch-depth-1 (T3 minimum 2-phase):
// next tile's global_load_lds issued BEFORE current tile's ds_read+MFMA, one barrier/step.
// Split-K via blockIdx.z for EP_BIAS_RES (atomicAdd f32 into resid; bias from split 0).
// NOTE: assumes (K / gridDim.z) % 64 == 0 (holds for all shapes used here).
__global__ __launch_bounds__(256)
void gemm_nt(const bf16_t* __restrict__ A, const bf16_t* __restrict__ B,
             const int K, const int N, const int mode,
             const float* __restrict__ sacc_p, const float sinvn, const float sbias,
             const float* __restrict__ bias,
             float* __restrict__ resid,
             bf16_t* __restrict__ outb)
{
  __shared__ __align__(16) bf16_t lsA[2][128 * 32];
  __shared__ __align__(16) bf16_t lsB[2][128 * 32];
  const int tid  = threadIdx.x;
  const int lane = tid & 63;
  const int wave = tid >> 6;
  const int wm = wave >> 1, wn = wave & 1;
  const int bm = blockIdx.x, bn = blockIdx.y;

  const int KL    = K / gridDim.z;          // K-length of this split
  const int kbase = blockIdx.z * KL;

  // DMA staging coords: wave w stages rows [w*32, w*32+32) of A-tile and B-tile,
  // 2 instructions each (16 rows = 1024B per instruction). Lane i of instruction
  // lands at tile byte offset w*2048 (+1024) + i*16 — linear, matches [128][32].
  const int srow = wave * 32 + (lane >> 2);
  const int scol = (lane & 3) * 8;
  const bf16_t* gA = A + (size_t)(bm * 128 + srow) * K + kbase + scol;
  const bf16_t* gB = B + (size_t)(bn * 128 + srow) * K + kbase + scol;
  const int l0 = srow * 32 + scol;
  const int l1 = (srow + 16) * 32 + scol;

  f32x4 acc[4][4];
#pragma unroll
  for (int i = 0; i < 4; i++)
#pragma unroll
    for (int j = 0; j < 4; j++) acc[i][j] = (f32x4){0.f, 0.f, 0.f, 0.f};

  const int arow = (wm * 64 + (lane & 15)) * 32 + (lane >> 4) * 8;
  const int brow = (wn * 64 + (lane & 15)) * 32 + (lane >> 4) * 8;

  auto stage = [&](int b, int kb) {
    gload_lds16(gA + kb,                  &lsA[b][l0]);
    gload_lds16(gA + (size_t)16 * K + kb, &lsA[b][l1]);
    gload_lds16(gB + kb,                  &lsB[b][l0]);
    gload_lds16(gB + (size_t)16 * K + kb, &lsB[b][l1]);
  };
  auto compute = [&](int b) {
    bf16x8 af[4], bfv[4];
#pragma unroll
    for (int i = 0; i < 4; i++) af[i]  = *(const bf16x8*)&lsA[b][arow + i * 16 * 32];
#pragma unroll
    for (int j = 0; j < 4; j++) bfv[j] = *(const bf16x8*)&lsB[b][brow + j * 16 * 32];
#pragma unroll
    for (int i = 0; i < 4; i++)
#pragma unroll
      for (int j = 0; j < 4; j++)
        acc[i][j] = __builtin_amdgcn_mfma_f32_16x16x32_bf16(af[i], bfv[j], acc[i][j], 0, 0, 0);
  };

  stage(0, 0);
  __syncthreads();                           // drain prologue loads
  for (int kb = 0; kb < KL; kb += 64) {
    if (kb + 32 < KL) stage(1, kb + 32);     // prefetch issued BEFORE compute
    compute(0);
    __syncthreads();                         // drain prefetch + protect buf0 reuse
    if (kb + 64 < KL) stage(0, kb + 64);
    compute(1);
    __syncthreads();
  }

  const float s = (*sacc_p) * sinvn + sbias;
  const int r0 = bm * 128 + wm * 64 + (lane >> 4) * 4;
  const int c0 = bn * 128 + wn * 64 + (lane & 15);
  const bool split   = (gridDim.z > 1);
  const bool dobias  = (blockIdx.z == 0);
#pragma unroll
  for (int i = 0; i < 4; i++) {
#pragma unroll
    for (int j = 0; j < 4; j++) {
      const int col = c0 + j * 16;
#pragma unroll
      for (int r = 0; r < 4; r++) {
        const int row = r0 + i * 16 + r;
        const float v = acc[i][j][r] * s;
        const size_t idx = (size_t)row * N + col;
        if (mode == EP_STORE) {
          outb[idx] = (bf16_t)v;
        } else if (mode == EP_BIAS_RES) {
          const float add = v + (dobias ? bias[col] : 0.f);
          if (split) atomicAdd(&resid[idx], add);
          else       resid[idx] += add;
        } else {  // EP_BIAS_GELU (exact gelu)
          const float t = v + bias[col];
          outb[idx] = (bf16_t)(0.5f * t * (1.0f + erff(t * 0.70710678118654752f)));
        }
      }
    }
  }
}

// ---------------- LayerNorm: one block per row; f32 gamma/beta; bf16 out -------------
template <typename TIN>
__global__ __launch_bounds__(256)
void ln_kern(const TIN* __restrict__ x, const float* __restrict__ g,
             const float* __restrict__ b, bf16_t* __restrict__ y, const int W)
{
  const int row = blockIdx.x;
  const int tid = threadIdx.x;
  const TIN* xr = x + (size_t)row * W;
  float s = 0.f, s2 = 0.f;
  for (int i = tid; i < W; i += 256) {
    const float v = (float)xr[i];
    s += v; s2 += v * v;
  }
#pragma unroll
  for (int off = 32; off > 0; off >>= 1) {
    s  += __shfl_xor(s,  off, 64);
    s2 += __shfl_xor(s2, off, 64);
  }
  __shared__ float red[8];
  if ((tid & 63) == 0) { red[(tid >> 6) * 2] = s; red[(tid >> 6) * 2 + 1] = s2; }
  __syncthreads();
  const float ts  = red[0] + red[2] + red[4] + red[6];
  const float ts2 = red[1] + red[3] + red[5] + red[7];
  const float invW = 1.0f / (float)W;
  const float mean = ts * invW;
  const float var  = fmaxf(ts2 * invW - mean * mean, 0.f);
  const float rs   = rsqrtf(var + 1e-5f);
  bf16_t* yr = y + (size_t)row * W;
  for (int i = tid; i < W; i += 256) {
    const float v = ((float)xr[i] - mean) * rs * g[i] + b[i];
    yr[i] = (bf16_t)v;
  }
}

// ---------------- MFMA flash attention ----------------
// grid (NSEQ/64, NH, NB), 256 threads = 4 waves. WG handles one (b,h) + 64 q rows;
// each wave owns 16 q rows. KV tiles of 64. 16x16x32 bf16 MFMA for QK^T and PV.
__global__ __launch_bounds__(256)
void attn_mfma(const bf16_t* __restrict__ qkv, bf16_t* __restrict__ o)
{
  __shared__ __align__(16) bf16_t Ks[64][72];      // K [kv][d], +8 pad
  __shared__ __align__(16) bf16_t Vt[64][72];      // V^T [d][kv], +8 pad
  __shared__ __align__(16) bf16_t Pw[4][16][72];   // per-wave P [q][kv], +8 pad
  const int tid  = threadIdx.x;
  const int lane = tid & 63;
  const int wave = tid >> 6;
  const int quad = lane >> 4;
  const int l15  = lane & 15;
  const int qb = blockIdx.x, hh = blockIdx.y, bb = blockIdx.z;
  const size_t tokbase = (size_t)bb * NSEQ;

  // Q A-fragments for this lane's q row: Q[qrow][kk*32 + quad*8 + j]
  const int qrow = qb * 64 + wave * 16 + l15;
  bf16x8 qf[2];
  {
    const bf16_t* qp = qkv + (tokbase + qrow) * QKVW + hh * DH;
    qf[0] = *(const bf16x8*)(qp + quad * 8);
    qf[1] = *(const bf16x8*)(qp + 32 + quad * 8);
  }

  f32x4 Ot[4];                       // O C-frags: col d = dt*16+l15, row q = quad*4+r
#pragma unroll
  for (int i = 0; i < 4; i++) Ot[i] = (f32x4){0.f, 0.f, 0.f, 0.f};
  float m_r[4], l_r[4];
#pragma unroll
  for (int r = 0; r < 4; r++) { m_r[r] = -1e30f; l_r[r] = 0.f; }

  // staging coords: thread -> kv row (tid&63), d-base (tid>>6)*16
  const int skv = tid & 63;
  const int sd  = (tid >> 6) * 16;

  for (int kt = 0; kt < NSEQ / 64; ++kt) {
    const bf16_t* kp = qkv + (tokbase + kt * 64 + skv) * QKVW + INNERV + hh * DH + sd;
    const bf16_t* vp = kp + INNERV;
    bf16x8 k0 = *(const bf16x8*)kp;
    bf16x8 k1 = *(const bf16x8*)(kp + 8);
    bf16x8 v0 = *(const bf16x8*)vp;
    bf16x8 v1 = *(const bf16x8*)(vp + 8);
    __syncthreads();                 // prev tile's LDS reads complete
    *(bf16x8*)&Ks[skv][sd]     = k0;
    *(bf16x8*)&Ks[skv][sd + 8] = k1;
#pragma unroll
    for (int e = 0; e < 8; e++) { Vt[sd + e][skv] = v0[e]; Vt[sd + 8 + e][skv] = v1[e]; }
    __syncthreads();

    // S = Q K^T : 4 col-tiles of 16 kv, 2 k-steps each
    f32x4 st[4];
#pragma unroll
    for (int nt = 0; nt < 4; nt++) {
      bf16x8 b0 = *(const bf16x8*)&Ks[nt * 16 + l15][quad * 8];
      bf16x8 b1 = *(const bf16x8*)&Ks[nt * 16 + l15][32 + quad * 8];
      f32x4 c = (f32x4){0.f, 0.f, 0.f, 0.f};
      c = __builtin_amdgcn_mfma_f32_16x16x32_bf16(qf[0], b0, c, 0, 0, 0);
      c = __builtin_amdgcn_mfma_f32_16x16x32_bf16(qf[1], b1, c, 0, 0, 0);
      st[nt] = c;
    }

    // online softmax; SCALE=0.125 folded here (S is f32)
    float rmax[4];
#pragma unroll
    for (int r = 0; r < 4; r++) {
      float v = fmaxf(fmaxf(st[0][r], st[1][r]), fmaxf(st[2][r], st[3][r]));
      v = fmaxf(v, __shfl_xor(v, 1, 64));
      v = fmaxf(v, __shfl_xor(v, 2, 64));
      v = fmaxf(v, __shfl_xor(v, 4, 64));
      v = fmaxf(v, __shfl_xor(v, 8, 64));
      rmax[r] = v * 0.125f;
    }
    float alpha[4];
#pragma unroll
    for (int r = 0; r < 4; r++) {
      const float mnew = fmaxf(m_r[r], rmax[r]);
      alpha[r] = __expf(m_r[r] - mnew);
      m_r[r] = mnew;
    }
    float rsum[4] = {0.f, 0.f, 0.f, 0.f};
#pragma unroll
    for (int nt = 0; nt < 4; nt++) {
#pragma unroll
      for (int r = 0; r < 4; r++) {
        const float p = __expf(st[nt][r] * 0.125f - m_r[r]);
        rsum[r] += p;
        Pw[wave][quad * 4 + r][nt * 16 + l15] = (bf16_t)p;
      }
    }
#pragma unroll
    for (int r = 0; r < 4; r++) {
      float v = rsum[r];
      v += __shfl_xor(v, 1, 64);
      v += __shfl_xor(v, 2, 64);
      v += __shfl_xor(v, 4, 64);
      v += __shfl_xor(v, 8, 64);
      l_r[r] = l_r[r] * alpha[r] + v;
    }
#pragma unroll
    for (int dt = 0; dt < 4; dt++)
#pragma unroll
      for (int r = 0; r < 4; r++) Ot[dt][r] *= alpha[r];

    __syncthreads();                 // Pw visible (wave-local slab, wg barrier is safe)

    // O += P V : A = P[q][kv], B = Vt[d][kv]
#pragma unroll
    for (int kk = 0; kk < 2; kk++) {
      bf16x8 pa = *(const bf16x8*)&Pw[wave][l15][kk * 32 + quad * 8];
#pragma unroll
      for (int dt = 0; dt < 4; dt++) {
        bf16x8 vb = *(const bf16x8*)&Vt[dt * 16 + l15][kk * 32 + quad * 8];
        Ot[dt] = __builtin_amdgcn_mfma_f32_16x16x32_bf16(pa, vb, Ot[dt], 0, 0, 0);
      }
    }
  }

  float inv[4];
#pragma unroll
  for (int r = 0; r < 4; r++) inv[r] = 1.0f / l_r[r];
#pragma unroll
  for (int dt = 0; dt < 4; dt++) {
#pragma unroll
    for (int r = 0; r < 4; r++) {
      const int q = qb * 64 + wave * 16 + quad * 4 + r;
      const int d = dt * 16 + l15;
      o[(tokbase + q) * INNERV + hh * DH + d] = (bf16_t)(Ot[dt][r] * inv[r]);
    }
  }
}

// ---------------- ternary quant helpers (f32 weights in) ----------------
__global__ __launch_bounds__(64)
void zero_kern(float* __restrict__ p)
{
  p[threadIdx.x] = 0.f;
}

__global__ __launch_bounds__(256)
void absmean_kern(const float* __restrict__ w, const long n, float* __restrict__ acc)
{
  const int tid = threadIdx.x;
  float s = 0.f;
  const size_t stride = (size_t)256 * gridDim.x * 4;
  for (size_t i = ((size_t)blockIdx.x * 256 + tid) * 4; i < (size_t)n; i += stride) {
    f32x4 t = *(const f32x4*)(w + i);
    s += fabsf(t[0]) + fabsf(t[1]) + fabsf(t[2]) + fabsf(t[3]);
  }
#pragma unroll
  for (int off = 32; off > 0; off >>= 1) s += __shfl_xor(s, off, 64);
  __shared__ float red[4];
  if ((tid & 63) == 0) red[tid >> 6] = s;
  __syncthreads();
  if (tid == 0) atomicAdd(acc, red[0] + red[1] + red[2] + red[3]);
}

// ternary: wq = clip(round(w/s), -1, 1) stored EXACTLY as bf16 {-1,0,1}; s applied in GEMM
__global__ __launch_bounds__(256)
void quant_kern(const float* __restrict__ w, bf16_t* __restrict__ wq,
                const int n, const float* __restrict__ acc, const float invn)
{
  const int i = blockIdx.x * 256 + threadIdx.x;
  if (i >= n) return;
  const float s = (*acc) * invn + 1e-8f;
  float q = rintf(w[i] / s);  // round-half-even, matches jnp.round
  q = fminf(1.f, fmaxf(-1.f, q));
  wq[i] = (bf16_t)q;
}

__global__ __launch_bounds__(256)
void copyf_kern(const float* __restrict__ in, float* __restrict__ out, const int n4)
{
  const int i = blockIdx.x * 256 + threadIdx.x;
  if (i < n4) ((f32x4*)out)[i] = ((const f32x4*)in)[i];
}

__global__ __launch_bounds__(256)
void f2b_kern(const float* __restrict__ in, bf16_t* __restrict__ out, const int n)
{
  const int i = blockIdx.x * 256 + threadIdx.x;
  if (i < n) out[i] = (bf16_t)in[i];
}

// ---------------- driver ----------------
extern "C" void kernel_launch(void* const* d_in, const int* in_sizes, int n_in,
                              void* d_out, int out_size, void* d_ws, size_t ws_size,
                              hipStream_t stream)
{
  // ALL inputs are float32 (per reference setup_inputs dtypes).
  const float* x     = (const float*)d_in[0];
  const float* ln1_g = (const float*)d_in[1];
  const float* ln1_b = (const float*)d_in[2];
  const float* Wqkv  = (const float*)d_in[3];
  const float* ln2_g = (const float*)d_in[4];
  const float* ln2_b = (const float*)d_in[5];
  const float* Wo    = (const float*)d_in[6];
  const float* bo    = (const float*)d_in[7];
  const float* fg1   = (const float*)d_in[8];
  const float* fb1   = (const float*)d_in[9];
  const float* W1    = (const float*)d_in[10];
  const float* b1    = (const float*)d_in[11];
  const float* fg2   = (const float*)d_in[12];
  const float* fb2   = (const float*)d_in[13];
  const float* W2    = (const float*)d_in[14];
  const float* b2    = (const float*)d_in[15];

  char* ws = (char*)d_ws;
  size_t off = 0;
  float*  sacc  = (float*)(ws + off);  off += 256;                         // scale sums; [63] stays 0
  float*  h     = (float*)(ws + off);  off += (size_t)TOKENS * DIMV * 4;   // 25.2 MB residual stream
  bf16_t* bigA  = (bf16_t*)(ws + off); off += (size_t)TOKENS * MLPW * 2;   // 50.3 MB LN outs / attn out
  bf16_t* bigB  = (bf16_t*)(ws + off); off += (size_t)TOKENS * MLPW * 2;   // 50.3 MB qkv / gelu out
  bf16_t* q_qkv = (bf16_t*)(ws + off); off += (size_t)QKVW * DIMV * 2;
  bf16_t* q_o   = (bf16_t*)(ws + off); off += (size_t)DIMV * INNERV * 2;
  bf16_t* q_1   = (bf16_t*)(ws + off); off += (size_t)MLPW * DIMV * 2;
  bf16_t* q_2   = (bf16_t*)(ws + off); off += (size_t)DIMV * MLPW * 2;     // total ~140 MB

  bf16_t* obuf   = bigA;                              // attn out (12.6 MB)
  bf16_t* ln2out = bigA + (size_t)TOKENS * INNERV;    // LN2 out

  zero_kern<<<1, 64, 0, stream>>>(sacc);
  copyf_kern<<<TOKENS * DIMV / 4 / 256, 256, 0, stream>>>(x, h, TOKENS * DIMV / 4);

  for (int lyr = 0; lyr < 6; ++lyr) {
    const float* wqkv_l = Wqkv + (size_t)lyr * QKVW * DIMV;
    const float* wo_l   = Wo   + (size_t)lyr * DIMV * INNERV;
    const float* w1_l   = W1   + (size_t)lyr * MLPW * DIMV;
    const float* w2_l   = W2   + (size_t)lyr * DIMV * MLPW;
    const float *sq, *so, *s1, *s2p;
    float iq, io, i1, i2, bq, bo2, bb1v, bb2v;
    if (lyr < 5) {
      absmean_kern<<<256, 256, 0, stream>>>(wqkv_l, (long)QKVW * DIMV, &sacc[lyr * 4 + 0]);
      absmean_kern<<<256, 256, 0, stream>>>(wo_l,   (long)DIMV * INNERV, &sacc[lyr * 4 + 1]);
      absmean_kern<<<256, 256, 0, stream>>>(w1_l,   (long)MLPW * DIMV, &sacc[lyr * 4 + 2]);
      absmean_kern<<<256, 256, 0, stream>>>(w2_l,   (long)DIMV * MLPW, &sacc[lyr * 4 + 3]);
      quant_kern<<<QKVW * DIMV / 256, 256, 0, stream>>>(wqkv_l, q_qkv, QKVW * DIMV, &sacc[lyr * 4 + 0], 1.0f / (QKVW * DIMV));
      quant_kern<<<DIMV * INNERV / 256, 256, 0, stream>>>(wo_l, q_o, DIMV * INNERV, &sacc[lyr * 4 + 1], 1.0f / (DIMV * INNERV));
      quant_kern<<<MLPW * DIMV / 256, 256, 0, stream>>>(w1_l, q_1, MLPW * DIMV, &sacc[lyr * 4 + 2], 1.0f / (MLPW * DIMV));
      quant_kern<<<DIMV * MLPW / 256, 256, 0, stream>>>(w2_l, q_2, DIMV * MLPW, &sacc[lyr * 4 + 3], 1.0f / (DIMV * MLPW));
      sq = &sacc[lyr * 4 + 0]; iq = 1.0f / (QKVW * DIMV); bq = 1e-8f;
      so = &sacc[lyr * 4 + 1]; io = 1.0f / (DIMV * INNERV); bo2 = 1e-8f;
      s1 = &sacc[lyr * 4 + 2]; i1 = 1.0f / (MLPW * DIMV); bb1v = 1e-8f;
      s2p = &sacc[lyr * 4 + 3]; i2 = 1.0f / (DIMV * MLPW); bb2v = 1e-8f;
    } else {
      // last layer: plain weights, bf16-cast, scale 1.0
      f2b_kern<<<QKVW * DIMV / 256, 256, 0, stream>>>(wqkv_l, q_qkv, QKVW * DIMV);
      f2b_kern<<<DIMV * INNERV / 256, 256, 0, stream>>>(wo_l, q_o, DIMV * INNERV);
      f2b_kern<<<MLPW * DIMV / 256, 256, 0, stream>>>(w1_l, q_1, MLPW * DIMV);
      f2b_kern<<<DIMV * MLPW / 256, 256, 0, stream>>>(w2_l, q_2, DIMV * MLPW);
      sq = so = s1 = s2p = &sacc[63];  // contains 0
      iq = io = i1 = i2 = 0.f;
      bq = bo2 = bb1v = bb2v = 1.0f;   // s = 0*0 + 1 = 1
    }

    // attention sub-block
    ln_kern<float><<<TOKENS, 256, 0, stream>>>(h, ln1_g + lyr * DIMV, ln1_b + lyr * DIMV, bigA, DIMV);
    gemm_nt<<<dim3(64, QKVW / 128), 256, 0, stream>>>(bigA, q_qkv, DIMV, QKVW, EP_STORE, sq, iq, bq, nullptr, nullptr, bigB);
    attn_mfma<<<dim3(NSEQ / 64, NH, NB), 256, 0, stream>>>(bigB, obuf);
    ln_kern<bf16_t><<<TOKENS, 256, 0, stream>>>(obuf, ln2_g + lyr * INNERV, ln2_b + lyr * INNERV, ln2out, INNERV);
    gemm_nt<<<dim3(64, DIMV / 128, 2), 256, 0, stream>>>(ln2out, q_o, INNERV, DIMV, EP_BIAS_RES, so, io, bo2, bo + lyr * DIMV, h, nullptr);
    // FF sub-block
    ln_kern<float><<<TOKENS, 256, 0, stream>>>(h, fg1 + lyr * DIMV, fb1 + lyr * DIMV, bigA, DIMV);
    gemm_nt<<<dim3(64, MLPW / 128), 256, 0, stream>>>(bigA, q_1, DIMV, MLPW, EP_BIAS_GELU, s1, i1, bb1v, b1 + lyr * MLPW, nullptr, bigB);
    ln_kern<bf16_t><<<TOKENS, 256, 0, stream>>>(bigB, fg2 + lyr * MLPW, fb2 + lyr * MLPW, bigA, MLPW);
    gemm_nt<<<dim3(64, DIMV / 128, 4), 256, 0, stream>>>(bigA, q_2, MLPW, DIMV, EP_BIAS_RES, s2p, i2, bb2v, b2 + lyr * DIMV, h, nullptr);
  }

  // OUTPUT IS FLOAT32 (reference returns f32) — copy residual stream directly.
  copyf_kern<<<TOKENS * DIMV / 4 / 256, 256, 0, stream>>>(h, (float*)d_out, TOKENS * DIMV / 4);
}

// Round 3
// 2942.453 us; speedup vs baseline: 1.0943x; 1.0943x over previous
//
#include <hip/hip_runtime.h>
#include <hip/hip_bf16.h>
#include <math.h>

typedef __bf16 bf16_t;
typedef __bf16 bf16x8 __attribute__((ext_vector_type(8)));
typedef float  f32x4  __attribute__((ext_vector_type(4)));

#define TOKENS 8192
#define DIMV   768
#define INNERV 768
#define QKVW   2304
#define MLPW   3072
#define NSEQ   1024
#define NB     8
#define NH     12
#define DH     64

enum { EP_STORE = 0, EP_BIAS_RES = 1, EP_BIAS_GELU = 2 };

// async global->LDS DMA, 16B per lane. LDS dest must be wave-uniform base + lane*16
// (our staging layout is exactly linear in lane order, so this holds).
__device__ __forceinline__ void gload_lds16(const bf16_t* g, bf16_t* l)
{
  __builtin_amdgcn_global_load_lds((const __attribute__((address_space(1))) void*)g,
                                   (__attribute__((address_space(3))) void*)l,
                                   16, 0, 0);
}

// ---------------- GEMM: C[M,N] = s * (A[M,K] * B[N,K]^T) + bias, bf16 in, f32 acc ----
// 128x128 tile, BK=32, double-buffered LDS, counted-vmcnt pipeline (T4):
//   prologue stages tiles 0,1 (8 loads/wave outstanding);
//   iter t: vmcnt(4) [tile t landed, t+1 STAYS IN FLIGHT] -> s_barrier -> compute(t)
//           -> lgkmcnt(0) -> s_barrier [buffer-reuse guard, NO vmcnt drain]
//           -> stage tile t+2 into t's buffer.
// vmcnt is per-wave FIFO (m135): each wave stages its own 4 loads/tile, so vmcnt(4)
// + barrier guarantees tile t fully in LDS across all waves.
__global__ __launch_bounds__(256)
void gemm_nt(const bf16_t* __restrict__ A, const bf16_t* __restrict__ B,
             const int K, const int N, const int mode,
             const float* __restrict__ sacc_p, const float sinvn, const float sbias,
             const float* __restrict__ bias,
             float* __restrict__ resid,
             bf16_t* __restrict__ outb)
{
  __shared__ __align__(16) bf16_t lsA[2][128 * 32];
  __shared__ __align__(16) bf16_t lsB[2][128 * 32];
  const int tid  = threadIdx.x;
  const int lane = tid & 63;
  const int wave = tid >> 6;
  const int wm = wave >> 1, wn = wave & 1;
  const int bm = blockIdx.x, bn = blockIdx.y;

  // staging coords: wave w stages rows [w*32, w*32+32) of A-tile and B-tile,
  // 2 instructions each (16 rows = 1024B per instruction), linear in lane order.
  const int srow = wave * 32 + (lane >> 2);
  const int scol = (lane & 3) * 8;
  const bf16_t* gA = A + (size_t)(bm * 128 + srow) * K + scol;
  const bf16_t* gB = B + (size_t)(bn * 128 + srow) * K + scol;
  const int l0 = srow * 32 + scol;
  const int l1 = (srow + 16) * 32 + scol;

  f32x4 acc[4][4];
#pragma unroll
  for (int i = 0; i < 4; i++)
#pragma unroll
    for (int j = 0; j < 4; j++) acc[i][j] = (f32x4){0.f, 0.f, 0.f, 0.f};

  const int arow = (wm * 64 + (lane & 15)) * 32 + (lane >> 4) * 8;
  const int brow = (wn * 64 + (lane & 15)) * 32 + (lane >> 4) * 8;

  auto stage = [&](int b, int kb) {
    gload_lds16(gA + kb,                  &lsA[b][l0]);
    gload_lds16(gA + (size_t)16 * K + kb, &lsA[b][l1]);
    gload_lds16(gB + kb,                  &lsB[b][l0]);
    gload_lds16(gB + (size_t)16 * K + kb, &lsB[b][l1]);
  };
  auto compute = [&](int b) {
    bf16x8 af[4], bfv[4];
#pragma unroll
    for (int i = 0; i < 4; i++) af[i]  = *(const bf16x8*)&lsA[b][arow + i * 16 * 32];
#pragma unroll
    for (int j = 0; j < 4; j++) bfv[j] = *(const bf16x8*)&lsB[b][brow + j * 16 * 32];
#pragma unroll
    for (int i = 0; i < 4; i++)
#pragma unroll
      for (int j = 0; j < 4; j++)
        acc[i][j] = __builtin_amdgcn_mfma_f32_16x16x32_bf16(af[i], bfv[j], acc[i][j], 0, 0, 0);
  };

  const int NT = K / 32;                     // >= 24 for all shapes here
  stage(0, 0);
  stage(1, 32);
  int cur = 0;
  for (int t = 0; t < NT - 1; ++t) {
    asm volatile("s_waitcnt vmcnt(4)" ::: "memory");   // tile t landed; t+1 in flight
    __builtin_amdgcn_s_barrier();
    __builtin_amdgcn_sched_barrier(0);                 // no ds_read hoists above barrier
    compute(cur);
    asm volatile("s_waitcnt lgkmcnt(0)" ::: "memory"); // our ds_reads of buf[cur] done
    __builtin_amdgcn_s_barrier();                      // all waves done reading buf[cur]
    __builtin_amdgcn_sched_barrier(0);                 // no stage hoists above barrier
    if (t + 2 < NT) stage(cur, (t + 2) * 32);
    cur ^= 1;
  }
  asm volatile("s_waitcnt vmcnt(0)" ::: "memory");
  __builtin_amdgcn_s_barrier();
  __builtin_amdgcn_sched_barrier(0);
  compute(cur);

  const float s = (*sacc_p) * sinvn + sbias;
  const int r0 = bm * 128 + wm * 64 + (lane >> 4) * 4;
  const int c0 = bn * 128 + wn * 64 + (lane & 15);
#pragma unroll
  for (int i = 0; i < 4; i++) {
#pragma unroll
    for (int j = 0; j < 4; j++) {
      const int col = c0 + j * 16;
#pragma unroll
      for (int r = 0; r < 4; r++) {
        const int row = r0 + i * 16 + r;
        const float v = acc[i][j][r] * s;
        const size_t idx = (size_t)row * N + col;
        if (mode == EP_STORE) {
          outb[idx] = (bf16_t)v;
        } else if (mode == EP_BIAS_RES) {
          resid[idx] += v + bias[col];
        } else {  // EP_BIAS_GELU (exact gelu)
          const float t = v + bias[col];
          outb[idx] = (bf16_t)(0.5f * t * (1.0f + erff(t * 0.70710678118654752f)));
        }
      }
    }
  }
}

// ---------------- LayerNorm: one block per row; f32 gamma/beta; bf16 out -------------
template <typename TIN>
__global__ __launch_bounds__(256)
void ln_kern(const TIN* __restrict__ x, const float* __restrict__ g,
             const float* __restrict__ b, bf16_t* __restrict__ y, const int W)
{
  const int row = blockIdx.x;
  const int tid = threadIdx.x;
  const TIN* xr = x + (size_t)row * W;
  float s = 0.f, s2 = 0.f;
  for (int i = tid; i < W; i += 256) {
    const float v = (float)xr[i];
    s += v; s2 += v * v;
  }
#pragma unroll
  for (int off = 32; off > 0; off >>= 1) {
    s  += __shfl_xor(s,  off, 64);
    s2 += __shfl_xor(s2, off, 64);
  }
  __shared__ float red[8];
  if ((tid & 63) == 0) { red[(tid >> 6) * 2] = s; red[(tid >> 6) * 2 + 1] = s2; }
  __syncthreads();
  const float ts  = red[0] + red[2] + red[4] + red[6];
  const float ts2 = red[1] + red[3] + red[5] + red[7];
  const float invW = 1.0f / (float)W;
  const float mean = ts * invW;
  const float var  = fmaxf(ts2 * invW - mean * mean, 0.f);
  const float rs   = rsqrtf(var + 1e-5f);
  bf16_t* yr = y + (size_t)row * W;
  for (int i = tid; i < W; i += 256) {
    const float v = ((float)xr[i] - mean) * rs * g[i] + b[i];
    yr[i] = (bf16_t)v;
  }
}

// ---------------- MFMA flash attention ----------------
// grid (NSEQ/64, NH, NB), 256 threads = 4 waves. WG handles one (b,h) + 64 q rows;
// each wave owns 16 q rows. KV tiles of 64. 16x16x32 bf16 MFMA for QK^T and PV.
__global__ __launch_bounds__(256)
void attn_mfma(const bf16_t* __restrict__ qkv, bf16_t* __restrict__ o)
{
  __shared__ __align__(16) bf16_t Ks[64][72];      // K [kv][d], +8 pad
  __shared__ __align__(16) bf16_t Vt[64][72];      // V^T [d][kv], +8 pad
  __shared__ __align__(16) bf16_t Pw[4][16][72];   // per-wave P [q][kv], +8 pad
  const int tid  = threadIdx.x;
  const int lane = tid & 63;
  const int wave = tid >> 6;
  const int quad = lane >> 4;
  const int l15  = lane & 15;
  const int qb = blockIdx.x, hh = blockIdx.y, bb = blockIdx.z;
  const size_t tokbase = (size_t)bb * NSEQ;

  // Q A-fragments for this lane's q row: Q[qrow][kk*32 + quad*8 + j]
  const int qrow = qb * 64 + wave * 16 + l15;
  bf16x8 qf[2];
  {
    const bf16_t* qp = qkv + (tokbase + qrow) * QKVW + hh * DH;
    qf[0] = *(const bf16x8*)(qp + quad * 8);
    qf[1] = *(const bf16x8*)(qp + 32 + quad * 8);
  }

  f32x4 Ot[4];                       // O C-frags: col d = dt*16+l15, row q = quad*4+r
#pragma unroll
  for (int i = 0; i < 4; i++) Ot[i] = (f32x4){0.f, 0.f, 0.f, 0.f};
  float m_r[4], l_r[4];
#pragma unroll
  for (int r = 0; r < 4; r++) { m_r[r] = -1e30f; l_r[r] = 0.f; }

  // staging coords: thread -> kv row (tid&63), d-base (tid>>6)*16
  const int skv = tid & 63;
  const int sd  = (tid >> 6) * 16;

  for (int kt = 0; kt < NSEQ / 64; ++kt) {
    const bf16_t* kp = qkv + (tokbase + kt * 64 + skv) * QKVW + INNERV + hh * DH + sd;
    const bf16_t* vp = kp + INNERV;
    bf16x8 k0 = *(const bf16x8*)kp;
    bf16x8 k1 = *(const bf16x8*)(kp + 8);
    bf16x8 v0 = *(const bf16x8*)vp;
    bf16x8 v1 = *(const bf16x8*)(vp + 8);
    __syncthreads();                 // prev tile's LDS reads complete
    *(bf16x8*)&Ks[skv][sd]     = k0;
    *(bf16x8*)&Ks[skv][sd + 8] = k1;
#pragma unroll
    for (int e = 0; e < 8; e++) { Vt[sd + e][skv] = v0[e]; Vt[sd + 8 + e][skv] = v1[e]; }
    __syncthreads();

    // S = Q K^T : 4 col-tiles of 16 kv, 2 k-steps each
    f32x4 st[4];
#pragma unroll
    for (int nt = 0; nt < 4; nt++) {
      bf16x8 b0 = *(const bf16x8*)&Ks[nt * 16 + l15][quad * 8];
      bf16x8 b1 = *(const bf16x8*)&Ks[nt * 16 + l15][32 + quad * 8];
      f32x4 c = (f32x4){0.f, 0.f, 0.f, 0.f};
      c = __builtin_amdgcn_mfma_f32_16x16x32_bf16(qf[0], b0, c, 0, 0, 0);
      c = __builtin_amdgcn_mfma_f32_16x16x32_bf16(qf[1], b1, c, 0, 0, 0);
      st[nt] = c;
    }

    // online softmax; SCALE=0.125 folded here (S is f32)
    float rmax[4];
#pragma unroll
    for (int r = 0; r < 4; r++) {
      float v = fmaxf(fmaxf(st[0][r], st[1][r]), fmaxf(st[2][r], st[3][r]));
      v = fmaxf(v, __shfl_xor(v, 1, 64));
      v = fmaxf(v, __shfl_xor(v, 2, 64));
      v = fmaxf(v, __shfl_xor(v, 4, 64));
      v = fmaxf(v, __shfl_xor(v, 8, 64));
      rmax[r] = v * 0.125f;
    }
    float alpha[4];
#pragma unroll
    for (int r = 0; r < 4; r++) {
      const float mnew = fmaxf(m_r[r], rmax[r]);
      alpha[r] = __expf(m_r[r] - mnew);
      m_r[r] = mnew;
    }
    float rsum[4] = {0.f, 0.f, 0.f, 0.f};
#pragma unroll
    for (int nt = 0; nt < 4; nt++) {
#pragma unroll
      for (int r = 0; r < 4; r++) {
        const float p = __expf(st[nt][r] * 0.125f - m_r[r]);
        rsum[r] += p;
        Pw[wave][quad * 4 + r][nt * 16 + l15] = (bf16_t)p;
      }
    }
#pragma unroll
    for (int r = 0; r < 4; r++) {
      float v = rsum[r];
      v += __shfl_xor(v, 1, 64);
      v += __shfl_xor(v, 2, 64);
      v += __shfl_xor(v, 4, 64);
      v += __shfl_xor(v, 8, 64);
      l_r[r] = l_r[r] * alpha[r] + v;
    }
#pragma unroll
    for (int dt = 0; dt < 4; dt++)
#pragma unroll
      for (int r = 0; r < 4; r++) Ot[dt][r] *= alpha[r];

    __syncthreads();                 // Pw visible (wave-local slab, wg barrier is safe)

    // O += P V : A = P[q][kv], B = Vt[d][kv]
#pragma unroll
    for (int kk = 0; kk < 2; kk++) {
      bf16x8 pa = *(const bf16x8*)&Pw[wave][l15][kk * 32 + quad * 8];
#pragma unroll
      for (int dt = 0; dt < 4; dt++) {
        bf16x8 vb = *(const bf16x8*)&Vt[dt * 16 + l15][kk * 32 + quad * 8];
        Ot[dt] = __builtin_amdgcn_mfma_f32_16x16x32_bf16(pa, vb, Ot[dt], 0, 0, 0);
      }
    }
  }

  float inv[4];
#pragma unroll
  for (int r = 0; r < 4; r++) inv[r] = 1.0f / l_r[r];
#pragma unroll
  for (int dt = 0; dt < 4; dt++) {
#pragma unroll
    for (int r = 0; r < 4; r++) {
      const int q = qb * 64 + wave * 16 + quad * 4 + r;
      const int d = dt * 16 + l15;
      o[(tokbase + q) * INNERV + hh * DH + d] = (bf16_t)(Ot[dt][r] * inv[r]);
    }
  }
}

// ---------------- ternary quant helpers (f32 weights in) ----------------
__global__ __launch_bounds__(64)
void zero_kern(float* __restrict__ p)
{
  p[threadIdx.x] = 0.f;
}

__global__ __launch_bounds__(256)
void absmean_kern(const float* __restrict__ w, const long n, float* __restrict__ acc)
{
  const int tid = threadIdx.x;
  float s = 0.f;
  const size_t stride = (size_t)256 * gridDim.x * 4;
  for (size_t i = ((size_t)blockIdx.x * 256 + tid) * 4; i < (size_t)n; i += stride) {
    f32x4 t = *(const f32x4*)(w + i);
    s += fabsf(t[0]) + fabsf(t[1]) + fabsf(t[2]) + fabsf(t[3]);
  }
#pragma unroll
  for (int off = 32; off > 0; off >>= 1) s += __shfl_xor(s, off, 64);
  __shared__ float red[4];
  if ((tid & 63) == 0) red[tid >> 6] = s;
  __syncthreads();
  if (tid == 0) atomicAdd(acc, red[0] + red[1] + red[2] + red[3]);
}

// ternary: wq = clip(round(w/s), -1, 1) stored EXACTLY as bf16 {-1,0,1}; s applied in GEMM
__global__ __launch_bounds__(256)
void quant_kern(const float* __restrict__ w, bf16_t* __restrict__ wq,
                const int n, const float* __restrict__ acc, const float invn)
{
  const int i = blockIdx.x * 256 + threadIdx.x;
  if (i >= n) return;
  const float s = (*acc) * invn + 1e-8f;
  float q = rintf(w[i] / s);  // round-half-even, matches jnp.round
  q = fminf(1.f, fmaxf(-1.f, q));
  wq[i] = (bf16_t)q;
}

__global__ __launch_bounds__(256)
void copyf_kern(const float* __restrict__ in, float* __restrict__ out, const int n4)
{
  const int i = blockIdx.x * 256 + threadIdx.x;
  if (i < n4) ((f32x4*)out)[i] = ((const f32x4*)in)[i];
}

__global__ __launch_bounds__(256)
void f2b_kern(const float* __restrict__ in, bf16_t* __restrict__ out, const int n)
{
  const int i = blockIdx.x * 256 + threadIdx.x;
  if (i < n) out[i] = (bf16_t)in[i];
}

// ---------------- driver ----------------
extern "C" void kernel_launch(void* const* d_in, const int* in_sizes, int n_in,
                              void* d_out, int out_size, void* d_ws, size_t ws_size,
                              hipStream_t stream)
{
  // ALL inputs are float32 (per reference setup_inputs dtypes).
  const float* x     = (const float*)d_in[0];
  const float* ln1_g = (const float*)d_in[1];
  const float* ln1_b = (const float*)d_in[2];
  const float* Wqkv  = (const float*)d_in[3];
  const float* ln2_g = (const float*)d_in[4];
  const float* ln2_b = (const float*)d_in[5];
  const float* Wo    = (const float*)d_in[6];
  const float* bo    = (const float*)d_in[7];
  const float* fg1   = (const float*)d_in[8];
  const float* fb1   = (const float*)d_in[9];
  const float* W1    = (const float*)d_in[10];
  const float* b1    = (const float*)d_in[11];
  const float* fg2   = (const float*)d_in[12];
  const float* fb2   = (const float*)d_in[13];
  const float* W2    = (const float*)d_in[14];
  const float* b2    = (const float*)d_in[15];

  char* ws = (char*)d_ws;
  size_t off = 0;
  float*  sacc  = (float*)(ws + off);  off += 256;                         // scale sums; [63] stays 0
  float*  h     = (float*)(ws + off);  off += (size_t)TOKENS * DIMV * 4;   // 25.2 MB residual stream
  bf16_t* bigA  = (bf16_t*)(ws + off); off += (size_t)TOKENS * MLPW * 2;   // 50.3 MB LN outs / attn out
  bf16_t* bigB  = (bf16_t*)(ws + off); off += (size_t)TOKENS * MLPW * 2;   // 50.3 MB qkv / gelu out
  bf16_t* q_qkv = (bf16_t*)(ws + off); off += (size_t)QKVW * DIMV * 2;
  bf16_t* q_o   = (bf16_t*)(ws + off); off += (size_t)DIMV * INNERV * 2;
  bf16_t* q_1   = (bf16_t*)(ws + off); off += (size_t)MLPW * DIMV * 2;
  bf16_t* q_2   = (bf16_t*)(ws + off); off += (size_t)DIMV * MLPW * 2;     // total ~140 MB

  bf16_t* obuf   = bigA;                              // attn out (12.6 MB)
  bf16_t* ln2out = bigA + (size_t)TOKENS * INNERV;    // LN2 out

  zero_kern<<<1, 64, 0, stream>>>(sacc);
  copyf_kern<<<TOKENS * DIMV / 4 / 256, 256, 0, stream>>>(x, h, TOKENS * DIMV / 4);

  for (int lyr = 0; lyr < 6; ++lyr) {
    const float* wqkv_l = Wqkv + (size_t)lyr * QKVW * DIMV;
    const float* wo_l   = Wo   + (size_t)lyr * DIMV * INNERV;
    const float* w1_l   = W1   + (size_t)lyr * MLPW * DIMV;
    const float* w2_l   = W2   + (size_t)lyr * DIMV * MLPW;
    const float *sq, *so, *s1, *s2p;
    float iq, io, i1, i2, bq, bo2, bb1v, bb2v;
    if (lyr < 5) {
      absmean_kern<<<256, 256, 0, stream>>>(wqkv_l, (long)QKVW * DIMV, &sacc[lyr * 4 + 0]);
      absmean_kern<<<256, 256, 0, stream>>>(wo_l,   (long)DIMV * INNERV, &sacc[lyr * 4 + 1]);
      absmean_kern<<<256, 256, 0, stream>>>(w1_l,   (long)MLPW * DIMV, &sacc[lyr * 4 + 2]);
      absmean_kern<<<256, 256, 0, stream>>>(w2_l,   (long)DIMV * MLPW, &sacc[lyr * 4 + 3]);
      quant_kern<<<QKVW * DIMV / 256, 256, 0, stream>>>(wqkv_l, q_qkv, QKVW * DIMV, &sacc[lyr * 4 + 0], 1.0f / (QKVW * DIMV));
      quant_kern<<<DIMV * INNERV / 256, 256, 0, stream>>>(wo_l, q_o, DIMV * INNERV, &sacc[lyr * 4 + 1], 1.0f / (DIMV * INNERV));
      quant_kern<<<MLPW * DIMV / 256, 256, 0, stream>>>(w1_l, q_1, MLPW * DIMV, &sacc[lyr * 4 + 2], 1.0f / (MLPW * DIMV));
      quant_kern<<<DIMV * MLPW / 256, 256, 0, stream>>>(w2_l, q_2, DIMV * MLPW, &sacc[lyr * 4 + 3], 1.0f / (DIMV * MLPW));
      sq = &sacc[lyr * 4 + 0]; iq = 1.0f / (QKVW * DIMV); bq = 1e-8f;
      so = &sacc[lyr * 4 + 1]; io = 1.0f / (DIMV * INNERV); bo2 = 1e-8f;
      s1 = &sacc[lyr * 4 + 2]; i1 = 1.0f / (MLPW * DIMV); bb1v = 1e-8f;
      s2p = &sacc[lyr * 4 + 3]; i2 = 1.0f / (DIMV * MLPW); bb2v = 1e-8f;
    } else {
      // last layer: plain weights, bf16-cast, scale 1.0
      f2b_kern<<<QKVW * DIMV / 256, 256, 0, stream>>>(wqkv_l, q_qkv, QKVW * DIMV);
      f2b_kern<<<DIMV * INNERV / 256, 256, 0, stream>>>(wo_l, q_o, DIMV * INNERV);
      f2b_kern<<<MLPW * DIMV / 256, 256, 0, stream>>>(w1_l, q_1, MLPW * DIMV);
      f2b_kern<<<DIMV * MLPW / 256, 256, 0, stream>>>(w2_l, q_2, DIMV * MLPW);
      sq = so = s1 = s2p = &sacc[63];  // contains 0
      iq = io = i1 = i2 = 0.f;
      bq = bo2 = bb1v = bb2v = 1.0f;   // s = 0*0 + 1 = 1
    }

    // attention sub-block
    ln_kern<float><<<TOKENS, 256, 0, stream>>>(h, ln1_g + lyr * DIMV, ln1_b + lyr * DIMV, bigA, DIMV);
    gemm_nt<<<dim3(64, QKVW / 128), 256, 0, stream>>>(bigA, q_qkv, DIMV, QKVW, EP_STORE, sq, iq, bq, nullptr, nullptr, bigB);
    attn_mfma<<<dim3(NSEQ / 64, NH, NB), 256, 0, stream>>>(bigB, obuf);
    ln_kern<bf16_t><<<TOKENS, 256, 0, stream>>>(obuf, ln2_g + lyr * INNERV, ln2_b + lyr * INNERV, ln2out, INNERV);
    gemm_nt<<<dim3(64, DIMV / 128), 256, 0, stream>>>(ln2out, q_o, INNERV, DIMV, EP_BIAS_RES, so, io, bo2, bo + lyr * DIMV, h, nullptr);
    // FF sub-block
    ln_kern<float><<<TOKENS, 256, 0, stream>>>(h, fg1 + lyr * DIMV, fb1 + lyr * DIMV, bigA, DIMV);
    gemm_nt<<<dim3(64, MLPW / 128), 256, 0, stream>>>(bigA, q_1, DIMV, MLPW, EP_BIAS_GELU, s1, i1, bb1v, b1 + lyr * MLPW, nullptr, bigB);
    ln_kern<bf16_t><<<TOKENS, 256, 0, stream>>>(bigB, fg2 + lyr * MLPW, fb2 + lyr * MLPW, bigA, MLPW);
    gemm_nt<<<dim3(64, DIMV / 128), 256, 0, stream>>>(bigA, q_2, MLPW, DIMV, EP_BIAS_RES, s2p, i2, bb2v, b2 + lyr * DIMV, h, nullptr);
  }

  // OUTPUT IS FLOAT32 (reference returns f32) — copy residual stream directly.
  copyf_kern<<<TOKENS * DIMV / 4 / 256, 256, 0, stream>>>(h, (float*)d_out, TOKENS * DIMV / 4);
}

// Round 4
// 2691.669 us; speedup vs baseline: 1.1962x; 1.0932x over previous
//
#include <hip/hip_runtime.h>
#include <hip/hip_bf16.h>
#include <math.h>

typedef __bf16 bf16_t;
typedef __bf16 bf16x4 __attribute__((ext_vector_type(4)));
typedef __bf16 bf16x8 __attribute__((ext_vector_type(8)));
typedef float  f32x4  __attribute__((ext_vector_type(4)));

#define TOKENS 8192
#define DIMV   768
#define INNERV 768
#define QKVW   2304
#define MLPW   3072
#define NSEQ   1024
#define NB     8
#define NH     12
#define DH     64

enum { EP_STORE = 0, EP_BIAS_RES = 1, EP_BIAS_GELU = 2 };

// async global->LDS DMA, 16B per lane. LDS dest must be wave-uniform base + lane*16
// (our staging layout is exactly linear in lane order, so this holds).
__device__ __forceinline__ void gload_lds16(const bf16_t* g, bf16_t* l)
{
  __builtin_amdgcn_global_load_lds((const __attribute__((address_space(1))) void*)g,
                                   (__attribute__((address_space(3))) void*)l,
                                   16, 0, 0);
}

// ---------------- GEMM: C[M,N] = s * (A[M,K] * B[N,K]^T) + bias, bf16 in, f32 acc ----
// 128x128 tile, BK=32, double-buffered LDS, counted-vmcnt pipeline (T4):
//   prologue stages tiles 0,1 (8 loads/wave outstanding);
//   iter t: vmcnt(4) [tile t landed, t+1 STAYS IN FLIGHT] -> s_barrier -> compute(t)
//           -> lgkmcnt(0) -> s_barrier [buffer-reuse guard, NO vmcnt drain]
//           -> stage tile t+2 into t's buffer.
__global__ __launch_bounds__(256)
void gemm_nt(const bf16_t* __restrict__ A, const bf16_t* __restrict__ B,
             const int K, const int N, const int mode,
             const float* __restrict__ sacc_p, const float sinvn, const float sbias,
             const float* __restrict__ bias,
             float* __restrict__ resid,
             bf16_t* __restrict__ outb)
{
  __shared__ __align__(16) bf16_t lsA[2][128 * 32];
  __shared__ __align__(16) bf16_t lsB[2][128 * 32];
  const int tid  = threadIdx.x;
  const int lane = tid & 63;
  const int wave = tid >> 6;
  const int wm = wave >> 1, wn = wave & 1;
  const int bm = blockIdx.x, bn = blockIdx.y;

  const int srow = wave * 32 + (lane >> 2);
  const int scol = (lane & 3) * 8;
  const bf16_t* gA = A + (size_t)(bm * 128 + srow) * K + scol;
  const bf16_t* gB = B + (size_t)(bn * 128 + srow) * K + scol;
  const int l0 = srow * 32 + scol;
  const int l1 = (srow + 16) * 32 + scol;

  f32x4 acc[4][4];
#pragma unroll
  for (int i = 0; i < 4; i++)
#pragma unroll
    for (int j = 0; j < 4; j++) acc[i][j] = (f32x4){0.f, 0.f, 0.f, 0.f};

  const int arow = (wm * 64 + (lane & 15)) * 32 + (lane >> 4) * 8;
  const int brow = (wn * 64 + (lane & 15)) * 32 + (lane >> 4) * 8;

  auto stage = [&](int b, int kb) {
    gload_lds16(gA + kb,                  &lsA[b][l0]);
    gload_lds16(gA + (size_t)16 * K + kb, &lsA[b][l1]);
    gload_lds16(gB + kb,                  &lsB[b][l0]);
    gload_lds16(gB + (size_t)16 * K + kb, &lsB[b][l1]);
  };
  auto compute = [&](int b) {
    bf16x8 af[4], bfv[4];
#pragma unroll
    for (int i = 0; i < 4; i++) af[i]  = *(const bf16x8*)&lsA[b][arow + i * 16 * 32];
#pragma unroll
    for (int j = 0; j < 4; j++) bfv[j] = *(const bf16x8*)&lsB[b][brow + j * 16 * 32];
#pragma unroll
    for (int i = 0; i < 4; i++)
#pragma unroll
      for (int j = 0; j < 4; j++)
        acc[i][j] = __builtin_amdgcn_mfma_f32_16x16x32_bf16(af[i], bfv[j], acc[i][j], 0, 0, 0);
  };

  const int NT = K / 32;
  stage(0, 0);
  stage(1, 32);
  int cur = 0;
  for (int t = 0; t < NT - 1; ++t) {
    asm volatile("s_waitcnt vmcnt(4)" ::: "memory");   // tile t landed; t+1 in flight
    __builtin_amdgcn_s_barrier();
    __builtin_amdgcn_sched_barrier(0);
    compute(cur);
    asm volatile("s_waitcnt lgkmcnt(0)" ::: "memory");
    __builtin_amdgcn_s_barrier();                      // all waves done reading buf[cur]
    __builtin_amdgcn_sched_barrier(0);
    if (t + 2 < NT) stage(cur, (t + 2) * 32);
    cur ^= 1;
  }
  asm volatile("s_waitcnt vmcnt(0)" ::: "memory");
  __builtin_amdgcn_s_barrier();
  __builtin_amdgcn_sched_barrier(0);
  compute(cur);

  const float s = (*sacc_p) * sinvn + sbias;
  const int r0 = bm * 128 + wm * 64 + (lane >> 4) * 4;
  const int c0 = bn * 128 + wn * 64 + (lane & 15);
#pragma unroll
  for (int i = 0; i < 4; i++) {
#pragma unroll
    for (int j = 0; j < 4; j++) {
      const int col = c0 + j * 16;
#pragma unroll
      for (int r = 0; r < 4; r++) {
        const int row = r0 + i * 16 + r;
        const float v = acc[i][j][r] * s;
        const size_t idx = (size_t)row * N + col;
        if (mode == EP_STORE) {
          outb[idx] = (bf16_t)v;
        } else if (mode == EP_BIAS_RES) {
          resid[idx] += v + bias[col];
        } else {  // EP_BIAS_GELU (exact gelu)
          const float t = v + bias[col];
          outb[idx] = (bf16_t)(0.5f * t * (1.0f + erff(t * 0.70710678118654752f)));
        }
      }
    }
  }
}

// ---------------- LayerNorm: one block per row; vectorized loads (G13) ----------------
template <typename TIN>
__global__ __launch_bounds__(256)
void ln_kern(const TIN* __restrict__ x, const float* __restrict__ g,
             const float* __restrict__ b, bf16_t* __restrict__ y, const int W)
{
  const int row = blockIdx.x;
  const int tid = threadIdx.x;
  const TIN* xr = x + (size_t)row * W;
  float s = 0.f, s2 = 0.f;
  if constexpr (sizeof(TIN) == 4) {
    const f32x4* xv = (const f32x4*)xr;
    for (int i = tid; i < W / 4; i += 256) {
      f32x4 v = xv[i];
#pragma unroll
      for (int e = 0; e < 4; e++) { s += v[e]; s2 += v[e] * v[e]; }
    }
  } else {
    const bf16x8* xv = (const bf16x8*)xr;
    for (int i = tid; i < W / 8; i += 256) {
      bf16x8 v = xv[i];
#pragma unroll
      for (int e = 0; e < 8; e++) { const float f = (float)v[e]; s += f; s2 += f * f; }
    }
  }
#pragma unroll
  for (int off = 32; off > 0; off >>= 1) {
    s  += __shfl_xor(s,  off, 64);
    s2 += __shfl_xor(s2, off, 64);
  }
  __shared__ float red[8];
  if ((tid & 63) == 0) { red[(tid >> 6) * 2] = s; red[(tid >> 6) * 2 + 1] = s2; }
  __syncthreads();
  const float ts  = red[0] + red[2] + red[4] + red[6];
  const float ts2 = red[1] + red[3] + red[5] + red[7];
  const float invW = 1.0f / (float)W;
  const float mean = ts * invW;
  const float var  = fmaxf(ts2 * invW - mean * mean, 0.f);
  const float rs   = rsqrtf(var + 1e-5f);
  bf16_t* yr = y + (size_t)row * W;
  const f32x4* gv = (const f32x4*)g;
  const f32x4* bv = (const f32x4*)b;
  if constexpr (sizeof(TIN) == 4) {
    const f32x4* xv = (const f32x4*)xr;
    bf16x4* yv = (bf16x4*)yr;
    for (int i = tid; i < W / 4; i += 256) {
      f32x4 v = xv[i], gg = gv[i], bb = bv[i];
      bf16x4 o;
#pragma unroll
      for (int e = 0; e < 4; e++) o[e] = (bf16_t)((v[e] - mean) * rs * gg[e] + bb[e]);
      yv[i] = o;
    }
  } else {
    const bf16x8* xv = (const bf16x8*)xr;
    bf16x8* yv = (bf16x8*)yr;
    for (int i = tid; i < W / 8; i += 256) {
      bf16x8 v = xv[i];
      f32x4 g0 = gv[2 * i], g1 = gv[2 * i + 1];
      f32x4 b0 = bv[2 * i], b1 = bv[2 * i + 1];
      bf16x8 o;
#pragma unroll
      for (int e = 0; e < 4; e++) o[e]     = (bf16_t)(((float)v[e]     - mean) * rs * g0[e] + b0[e]);
#pragma unroll
      for (int e = 0; e < 4; e++) o[e + 4] = (bf16_t)(((float)v[e + 4] - mean) * rs * g1[e] + b1[e]);
      yv[i] = o;
    }
  }
}

// ---------------- MFMA flash attention ----------------
// grid (NSEQ/64, NH, NB), 256 threads = 4 waves. WG handles one (b,h) + 64 q rows;
// each wave owns 16 q rows. KV tiles of 64. 16x16x32 bf16 MFMA for QK^T and PV.
// T14 async-stage: tile kt+1's K/V global loads issued right after tile kt's LDS
// writes -> in flight across QK^T+softmax+PV. Pw is wave-private: lgkmcnt(0) only.
__global__ __launch_bounds__(256)
void attn_mfma(const bf16_t* __restrict__ qkv, bf16_t* __restrict__ o)
{
  __shared__ __align__(16) bf16_t Ks[64][72];      // K [kv][d], +8 pad
  __shared__ __align__(16) bf16_t Vt[64][72];      // V^T [d][kv], +8 pad
  __shared__ __align__(16) bf16_t Pw[4][16][72];   // per-wave P [q][kv], +8 pad
  const int tid  = threadIdx.x;
  const int lane = tid & 63;
  const int wave = tid >> 6;
  const int quad = lane >> 4;
  const int l15  = lane & 15;
  const int qb = blockIdx.x, hh = blockIdx.y, bb = blockIdx.z;
  const size_t tokbase = (size_t)bb * NSEQ;

  // Q A-fragments for this lane's q row: Q[qrow][kk*32 + quad*8 + j]
  const int qrow = qb * 64 + wave * 16 + l15;
  bf16x8 qf[2];
  {
    const bf16_t* qp = qkv + (tokbase + qrow) * QKVW + hh * DH;
    qf[0] = *(const bf16x8*)(qp + quad * 8);
    qf[1] = *(const bf16x8*)(qp + 32 + quad * 8);
  }

  f32x4 Ot[4];                       // O C-frags: col d = dt*16+l15, row q = quad*4+r
#pragma unroll
  for (int i = 0; i < 4; i++) Ot[i] = (f32x4){0.f, 0.f, 0.f, 0.f};
  float m_r[4], l_r[4];
#pragma unroll
  for (int r = 0; r < 4; r++) { m_r[r] = -1e30f; l_r[r] = 0.f; }

  // staging coords: thread -> kv row (tid&63), d-base (tid>>6)*16
  const int skv = tid & 63;
  const int sd  = (tid >> 6) * 16;

  // prologue: tile 0 K/V into registers
  bf16x8 k0, k1, v0, v1;
  {
    const bf16_t* kp = qkv + (tokbase + skv) * QKVW + INNERV + hh * DH + sd;
    k0 = *(const bf16x8*)kp;
    k1 = *(const bf16x8*)(kp + 8);
    v0 = *(const bf16x8*)(kp + INNERV);
    v1 = *(const bf16x8*)(kp + INNERV + 8);
  }

  for (int kt = 0; kt < NSEQ / 64; ++kt) {
    __syncthreads();                 // all waves done reading prev tile's Ks/Vt
    *(bf16x8*)&Ks[skv][sd]     = k0;
    *(bf16x8*)&Ks[skv][sd + 8] = k1;
#pragma unroll
    for (int e = 0; e < 8; e++) { Vt[sd + e][skv] = v0[e]; Vt[sd + 8 + e][skv] = v1[e]; }
    __syncthreads();

    // issue next tile's loads NOW — in flight across the whole compute phase (T14)
    bf16x8 nk0 = k0, nk1 = k1, nv0 = v0, nv1 = v1;
    if (kt + 1 < NSEQ / 64) {
      const bf16_t* kp = qkv + (tokbase + (kt + 1) * 64 + skv) * QKVW + INNERV + hh * DH + sd;
      nk0 = *(const bf16x8*)kp;
      nk1 = *(const bf16x8*)(kp + 8);
      nv0 = *(const bf16x8*)(kp + INNERV);
      nv1 = *(const bf16x8*)(kp + INNERV + 8);
    }

    // S = Q K^T : 4 col-tiles of 16 kv, 2 k-steps each
    f32x4 st[4];
#pragma unroll
    for (int nt = 0; nt < 4; nt++) {
      bf16x8 b0 = *(const bf16x8*)&Ks[nt * 16 + l15][quad * 8];
      bf16x8 b1 = *(const bf16x8*)&Ks[nt * 16 + l15][32 + quad * 8];
      f32x4 c = (f32x4){0.f, 0.f, 0.f, 0.f};
      c = __builtin_amdgcn_mfma_f32_16x16x32_bf16(qf[0], b0, c, 0, 0, 0);
      c = __builtin_amdgcn_mfma_f32_16x16x32_bf16(qf[1], b1, c, 0, 0, 0);
      st[nt] = c;
    }

    // online softmax; SCALE=0.125 folded here (S is f32)
    float rmax[4];
#pragma unroll
    for (int r = 0; r < 4; r++) {
      float v = fmaxf(fmaxf(st[0][r], st[1][r]), fmaxf(st[2][r], st[3][r]));
      v = fmaxf(v, __shfl_xor(v, 1, 64));
      v = fmaxf(v, __shfl_xor(v, 2, 64));
      v = fmaxf(v, __shfl_xor(v, 4, 64));
      v = fmaxf(v, __shfl_xor(v, 8, 64));
      rmax[r] = v * 0.125f;
    }
    float alpha[4];
#pragma unroll
    for (int r = 0; r < 4; r++) {
      const float mnew = fmaxf(m_r[r], rmax[r]);
      alpha[r] = __expf(m_r[r] - mnew);
      m_r[r] = mnew;
    }
    float rsum[4] = {0.f, 0.f, 0.f, 0.f};
#pragma unroll
    for (int nt = 0; nt < 4; nt++) {
#pragma unroll
      for (int r = 0; r < 4; r++) {
        const float p = __expf(st[nt][r] * 0.125f - m_r[r]);
        rsum[r] += p;
        Pw[wave][quad * 4 + r][nt * 16 + l15] = (bf16_t)p;
      }
    }
#pragma unroll
    for (int r = 0; r < 4; r++) {
      float v = rsum[r];
      v += __shfl_xor(v, 1, 64);
      v += __shfl_xor(v, 2, 64);
      v += __shfl_xor(v, 4, 64);
      v += __shfl_xor(v, 8, 64);
      l_r[r] = l_r[r] * alpha[r] + v;
    }
#pragma unroll
    for (int dt = 0; dt < 4; dt++)
#pragma unroll
      for (int r = 0; r < 4; r++) Ot[dt][r] *= alpha[r];

    // Pw slab is WAVE-PRIVATE: own-wave LDS drain suffices (no block barrier).
    asm volatile("s_waitcnt lgkmcnt(0)" ::: "memory");
    __builtin_amdgcn_sched_barrier(0);               // rule #18: pin reads below wait

    // O += P V : A = P[q][kv], B = Vt[d][kv]
#pragma unroll
    for (int kk = 0; kk < 2; kk++) {
      bf16x8 pa = *(const bf16x8*)&Pw[wave][l15][kk * 32 + quad * 8];
#pragma unroll
      for (int dt = 0; dt < 4; dt++) {
        bf16x8 vb = *(const bf16x8*)&Vt[dt * 16 + l15][kk * 32 + quad * 8];
        Ot[dt] = __builtin_amdgcn_mfma_f32_16x16x32_bf16(pa, vb, Ot[dt], 0, 0, 0);
      }
    }

    k0 = nk0; k1 = nk1; v0 = nv0; v1 = nv1;
  }

  float inv[4];
#pragma unroll
  for (int r = 0; r < 4; r++) inv[r] = 1.0f / l_r[r];
#pragma unroll
  for (int dt = 0; dt < 4; dt++) {
#pragma unroll
    for (int r = 0; r < 4; r++) {
      const int q = qb * 64 + wave * 16 + quad * 4 + r;
      const int d = dt * 16 + l15;
      o[(tokbase + q) * INNERV + hh * DH + d] = (bf16_t)(Ot[dt][r] * inv[r]);
    }
  }
}

// ---------------- ternary quant helpers (f32 weights in) ----------------
__global__ __launch_bounds__(64)
void zero_kern(float* __restrict__ p)
{
  p[threadIdx.x] = 0.f;
}

__global__ __launch_bounds__(256)
void absmean_kern(const float* __restrict__ w, const long n, float* __restrict__ acc)
{
  const int tid = threadIdx.x;
  float s = 0.f;
  const size_t stride = (size_t)256 * gridDim.x * 4;
  for (size_t i = ((size_t)blockIdx.x * 256 + tid) * 4; i < (size_t)n; i += stride) {
    f32x4 t = *(const f32x4*)(w + i);
    s += fabsf(t[0]) + fabsf(t[1]) + fabsf(t[2]) + fabsf(t[3]);
  }
#pragma unroll
  for (int off = 32; off > 0; off >>= 1) s += __shfl_xor(s, off, 64);
  __shared__ float red[4];
  if ((tid & 63) == 0) red[tid >> 6] = s;
  __syncthreads();
  if (tid == 0) atomicAdd(acc, red[0] + red[1] + red[2] + red[3]);
}

// ternary: wq = clip(round(w/s), -1, 1) stored EXACTLY as bf16 {-1,0,1}; s applied
// in GEMM. Vectorized x4 (all weight counts divisible by 1024).
__global__ __launch_bounds__(256)
void quant_kern(const float* __restrict__ w, bf16_t* __restrict__ wq,
                const int n4, const float* __restrict__ acc, const float invn)
{
  const int i = blockIdx.x * 256 + threadIdx.x;
  if (i >= n4) return;
  const float s = (*acc) * invn + 1e-8f;
  f32x4 t = ((const f32x4*)w)[i];
  bf16x4 o;
#pragma unroll
  for (int e = 0; e < 4; e++) {
    float q = rintf(t[e] / s);  // round-half-even, matches jnp.round
    q = fminf(1.f, fmaxf(-1.f, q));
    o[e] = (bf16_t)q;
  }
  ((bf16x4*)wq)[i] = o;
}

__global__ __launch_bounds__(256)
void copyf_kern(const float* __restrict__ in, float* __restrict__ out, const int n4)
{
  const int i = blockIdx.x * 256 + threadIdx.x;
  if (i < n4) ((f32x4*)out)[i] = ((const f32x4*)in)[i];
}

__global__ __launch_bounds__(256)
void f2b_kern(const float* __restrict__ in, bf16_t* __restrict__ out, const int n4)
{
  const int i = blockIdx.x * 256 + threadIdx.x;
  if (i >= n4) return;
  f32x4 t = ((const f32x4*)in)[i];
  bf16x4 o;
#pragma unroll
  for (int e = 0; e < 4; e++) o[e] = (bf16_t)t[e];
  ((bf16x4*)out)[i] = o;
}

// ---------------- driver ----------------
extern "C" void kernel_launch(void* const* d_in, const int* in_sizes, int n_in,
                              void* d_out, int out_size, void* d_ws, size_t ws_size,
                              hipStream_t stream)
{
  // ALL inputs are float32 (per reference setup_inputs dtypes).
  const float* x     = (const float*)d_in[0];
  const float* ln1_g = (const float*)d_in[1];
  const float* ln1_b = (const float*)d_in[2];
  const float* Wqkv  = (const float*)d_in[3];
  const float* ln2_g = (const float*)d_in[4];
  const float* ln2_b = (const float*)d_in[5];
  const float* Wo    = (const float*)d_in[6];
  const float* bo    = (const float*)d_in[7];
  const float* fg1   = (const float*)d_in[8];
  const float* fb1   = (const float*)d_in[9];
  const float* W1    = (const float*)d_in[10];
  const float* b1    = (const float*)d_in[11];
  const float* fg2   = (const float*)d_in[12];
  const float* fb2   = (const float*)d_in[13];
  const float* W2    = (const float*)d_in[14];
  const float* b2    = (const float*)d_in[15];

  char* ws = (char*)d_ws;
  size_t off = 0;
  float*  sacc  = (float*)(ws + off);  off += 256;                         // scale sums; [63] stays 0
  float*  h     = (float*)(ws + off);  off += (size_t)TOKENS * DIMV * 4;   // 25.2 MB residual stream
  bf16_t* bigA  = (bf16_t*)(ws + off); off += (size_t)TOKENS * MLPW * 2;   // 50.3 MB LN outs / attn out
  bf16_t* bigB  = (bf16_t*)(ws + off); off += (size_t)TOKENS * MLPW * 2;   // 50.3 MB qkv / gelu out
  bf16_t* q_qkv = (bf16_t*)(ws + off); off += (size_t)QKVW * DIMV * 2;
  bf16_t* q_o   = (bf16_t*)(ws + off); off += (size_t)DIMV * INNERV * 2;
  bf16_t* q_1   = (bf16_t*)(ws + off); off += (size_t)MLPW * DIMV * 2;
  bf16_t* q_2   = (bf16_t*)(ws + off); off += (size_t)DIMV * MLPW * 2;     // total ~140 MB

  bf16_t* obuf   = bigA;                              // attn out (12.6 MB)
  bf16_t* ln2out = bigA + (size_t)TOKENS * INNERV;    // LN2 out

  zero_kern<<<1, 64, 0, stream>>>(sacc);
  copyf_kern<<<TOKENS * DIMV / 4 / 256, 256, 0, stream>>>(x, h, TOKENS * DIMV / 4);

  for (int lyr = 0; lyr < 6; ++lyr) {
    const float* wqkv_l = Wqkv + (size_t)lyr * QKVW * DIMV;
    const float* wo_l   = Wo   + (size_t)lyr * DIMV * INNERV;
    const float* w1_l   = W1   + (size_t)lyr * MLPW * DIMV;
    const float* w2_l   = W2   + (size_t)lyr * DIMV * MLPW;
    const float *sq, *so, *s1, *s2p;
    float iq, io, i1, i2, bq, bo2, bb1v, bb2v;
    if (lyr < 5) {
      absmean_kern<<<256, 256, 0, stream>>>(wqkv_l, (long)QKVW * DIMV, &sacc[lyr * 4 + 0]);
      absmean_kern<<<256, 256, 0, stream>>>(wo_l,   (long)DIMV * INNERV, &sacc[lyr * 4 + 1]);
      absmean_kern<<<256, 256, 0, stream>>>(w1_l,   (long)MLPW * DIMV, &sacc[lyr * 4 + 2]);
      absmean_kern<<<256, 256, 0, stream>>>(w2_l,   (long)DIMV * MLPW, &sacc[lyr * 4 + 3]);
      quant_kern<<<QKVW * DIMV / 1024, 256, 0, stream>>>(wqkv_l, q_qkv, QKVW * DIMV / 4, &sacc[lyr * 4 + 0], 1.0f / (QKVW * DIMV));
      quant_kern<<<DIMV * INNERV / 1024, 256, 0, stream>>>(wo_l, q_o, DIMV * INNERV / 4, &sacc[lyr * 4 + 1], 1.0f / (DIMV * INNERV));
      quant_kern<<<MLPW * DIMV / 1024, 256, 0, stream>>>(w1_l, q_1, MLPW * DIMV / 4, &sacc[lyr * 4 + 2], 1.0f / (MLPW * DIMV));
      quant_kern<<<DIMV * MLPW / 1024, 256, 0, stream>>>(w2_l, q_2, DIMV * MLPW / 4, &sacc[lyr * 4 + 3], 1.0f / (DIMV * MLPW));
      sq = &sacc[lyr * 4 + 0]; iq = 1.0f / (QKVW * DIMV); bq = 1e-8f;
      so = &sacc[lyr * 4 + 1]; io = 1.0f / (DIMV * INNERV); bo2 = 1e-8f;
      s1 = &sacc[lyr * 4 + 2]; i1 = 1.0f / (MLPW * DIMV); bb1v = 1e-8f;
      s2p = &sacc[lyr * 4 + 3]; i2 = 1.0f / (DIMV * MLPW); bb2v = 1e-8f;
    } else {
      // last layer: plain weights, bf16-cast, scale 1.0
      f2b_kern<<<QKVW * DIMV / 1024, 256, 0, stream>>>(wqkv_l, q_qkv, QKVW * DIMV / 4);
      f2b_kern<<<DIMV * INNERV / 1024, 256, 0, stream>>>(wo_l, q_o, DIMV * INNERV / 4);
      f2b_kern<<<MLPW * DIMV / 1024, 256, 0, stream>>>(w1_l, q_1, MLPW * DIMV / 4);
      f2b_kern<<<DIMV * MLPW / 1024, 256, 0, stream>>>(w2_l, q_2, DIMV * MLPW / 4);
      sq = so = s1 = s2p = &sacc[63];  // contains 0
      iq = io = i1 = i2 = 0.f;
      bq = bo2 = bb1v = bb2v = 1.0f;   // s = 0*0 + 1 = 1
    }

    // attention sub-block
    ln_kern<float><<<TOKENS, 256, 0, stream>>>(h, ln1_g + lyr * DIMV, ln1_b + lyr * DIMV, bigA, DIMV);
    gemm_nt<<<dim3(64, QKVW / 128), 256, 0, stream>>>(bigA, q_qkv, DIMV, QKVW, EP_STORE, sq, iq, bq, nullptr, nullptr, bigB);
    attn_mfma<<<dim3(NSEQ / 64, NH, NB), 256, 0, stream>>>(bigB, obuf);
    ln_kern<bf16_t><<<TOKENS, 256, 0, stream>>>(obuf, ln2_g + lyr * INNERV, ln2_b + lyr * INNERV, ln2out, INNERV);
    gemm_nt<<<dim3(64, DIMV / 128), 256, 0, stream>>>(ln2out, q_o, INNERV, DIMV, EP_BIAS_RES, so, io, bo2, bo + lyr * DIMV, h, nullptr);
    // FF sub-block
    ln_kern<float><<<TOKENS, 256, 0, stream>>>(h, fg1 + lyr * DIMV, fb1 + lyr * DIMV, bigA, DIMV);
    gemm_nt<<<dim3(64, MLPW / 128), 256, 0, stream>>>(bigA, q_1, DIMV, MLPW, EP_BIAS_GELU, s1, i1, bb1v, b1 + lyr * MLPW, nullptr, bigB);
    ln_kern<bf16_t><<<TOKENS, 256, 0, stream>>>(bigB, fg2 + lyr * MLPW, fb2 + lyr * MLPW, bigA, MLPW);
    gemm_nt<<<dim3(64, DIMV / 128), 256, 0, stream>>>(bigA, q_2, MLPW, DIMV, EP_BIAS_RES, s2p, i2, bb2v, b2 + lyr * DIMV, h, nullptr);
  }

  // OUTPUT IS FLOAT32 (reference returns f32) — copy residual stream directly.
  copyf_kern<<<TOKENS * DIMV / 4 / 256, 256, 0, stream>>>(h, (float*)d_out, TOKENS * DIMV / 4);
}

// Round 5
// 2590.545 us; speedup vs baseline: 1.2429x; 1.0390x over previous
//
#include <hip/hip_runtime.h>
#include <hip/hip_bf16.h>
#include <math.h>

typedef __bf16 bf16_t;
typedef __bf16 bf16x4 __attribute__((ext_vector_type(4)));
typedef __bf16 bf16x8 __attribute__((ext_vector_type(8)));
typedef float  f32x4  __attribute__((ext_vector_type(4)));

#define TOKENS 8192
#define DIMV   768
#define INNERV 768
#define QKVW   2304
#define MLPW   3072
#define NSEQ   1024
#define NB     8
#define NH     12
#define DH     64

enum { EP_STORE = 0, EP_BIAS_RES = 1, EP_BIAS_GELU = 2 };

// async global->LDS DMA, 16B per lane. LDS dest must be wave-uniform base + lane*16.
__device__ __forceinline__ void gload_lds16(const bf16_t* g, bf16_t* l)
{
  __builtin_amdgcn_global_load_lds((const __attribute__((address_space(1))) void*)g,
                                   (__attribute__((address_space(3))) void*)l,
                                   16, 0, 0);
}

// ---------------- GEMM: C[M,N] = s * (A[M,K] * B[N,K]^T) + bias, bf16 in, f32 acc ----
// 128x128 tile, BK=32, double-buffered LDS, counted-vmcnt pipeline (T4) +
// T2 bank-conflict swizzle (rule #21 both-sides): LDS dest LINEAR (gload_lds
// requirement); global source col-slot XOR'd by f(row)=(row>>1)&3; fragment reads
// XOR the same f. f is invariant under row+16, so both staging rows share one
// pre-swizzled pointer and the i*16 read stride needs no re-swizzle.
// Bank spread after swizzle: 2-way max (free, m136).
__global__ __launch_bounds__(256)
void gemm_nt(const bf16_t* __restrict__ A, const bf16_t* __restrict__ B,
             const int K, const int N, const int mode,
             const float* __restrict__ sacc_p, const float sinvn, const float sbias,
             const float* __restrict__ bias,
             float* __restrict__ resid,
             bf16_t* __restrict__ outb,
             float* __restrict__ fout)   // if non-null (EP_BIAS_RES): fout = resid + v + bias
{
  __shared__ __align__(16) bf16_t lsA[2][128 * 32];
  __shared__ __align__(16) bf16_t lsB[2][128 * 32];
  const int tid  = threadIdx.x;
  const int lane = tid & 63;
  const int wave = tid >> 6;
  const int wm = wave >> 1, wn = wave & 1;
  const int bm = blockIdx.x, bn = blockIdx.y;

  // staging: wave w stages rows [w*32, w*32+32), 16B/lane, LDS linear.
  const int srow = wave * 32 + (lane >> 2);
  const int fsw  = (srow >> 1) & 3;                  // source-swizzle (same for srow+16)
  const int scol = ((lane & 3) ^ fsw) * 8;           // pre-swizzled GLOBAL col
  const bf16_t* gA = A + (size_t)(bm * 128 + srow) * K + scol;
  const bf16_t* gB = B + (size_t)(bn * 128 + srow) * K + scol;
  const int l0 = srow * 32 + (lane & 3) * 8;         // LINEAR LDS dest
  const int l1 = (srow + 16) * 32 + (lane & 3) * 8;

  f32x4 acc[4][4];
#pragma unroll
  for (int i = 0; i < 4; i++)
#pragma unroll
    for (int j = 0; j < 4; j++) acc[i][j] = (f32x4){0.f, 0.f, 0.f, 0.f};

  // fragment reads: row = wm*64 + l15 (+ i*16); col-slot = quad ^ f(row).
  const int fr   = ((lane & 15) >> 1) & 3;
  const int rsl  = ((lane >> 4) ^ fr) * 8;
  const int arow = (wm * 64 + (lane & 15)) * 32 + rsl;
  const int brow = (wn * 64 + (lane & 15)) * 32 + rsl;

  auto stage = [&](int b, int kb) {
    gload_lds16(gA + kb,                  &lsA[b][l0]);
    gload_lds16(gA + (size_t)16 * K + kb, &lsA[b][l1]);
    gload_lds16(gB + kb,                  &lsB[b][l0]);
    gload_lds16(gB + (size_t)16 * K + kb, &lsB[b][l1]);
  };
  auto compute = [&](int b) {
    bf16x8 af[4], bfv[4];
#pragma unroll
    for (int i = 0; i < 4; i++) af[i]  = *(const bf16x8*)&lsA[b][arow + i * 16 * 32];
#pragma unroll
    for (int j = 0; j < 4; j++) bfv[j] = *(const bf16x8*)&lsB[b][brow + j * 16 * 32];
#pragma unroll
    for (int i = 0; i < 4; i++)
#pragma unroll
      for (int j = 0; j < 4; j++)
        acc[i][j] = __builtin_amdgcn_mfma_f32_16x16x32_bf16(af[i], bfv[j], acc[i][j], 0, 0, 0);
  };

  const int NT = K / 32;
  stage(0, 0);
  stage(1, 32);
  int cur = 0;
  for (int t = 0; t < NT - 1; ++t) {
    asm volatile("s_waitcnt vmcnt(4)" ::: "memory");   // tile t landed; t+1 in flight
    __builtin_amdgcn_s_barrier();
    __builtin_amdgcn_sched_barrier(0);
    compute(cur);
    asm volatile("s_waitcnt lgkmcnt(0)" ::: "memory");
    __builtin_amdgcn_s_barrier();                      // all waves done reading buf[cur]
    __builtin_amdgcn_sched_barrier(0);
    if (t + 2 < NT) stage(cur, (t + 2) * 32);
    cur ^= 1;
  }
  asm volatile("s_waitcnt vmcnt(0)" ::: "memory");
  __builtin_amdgcn_s_barrier();
  __builtin_amdgcn_sched_barrier(0);
  compute(cur);

  const float s = (*sacc_p) * sinvn + sbias;
  const int r0 = bm * 128 + wm * 64 + (lane >> 4) * 4;
  const int c0 = bn * 128 + wn * 64 + (lane & 15);
#pragma unroll
  for (int i = 0; i < 4; i++) {
#pragma unroll
    for (int j = 0; j < 4; j++) {
      const int col = c0 + j * 16;
#pragma unroll
      for (int r = 0; r < 4; r++) {
        const int row = r0 + i * 16 + r;
        const float v = acc[i][j][r] * s;
        const size_t idx = (size_t)row * N + col;
        if (mode == EP_STORE) {
          outb[idx] = (bf16_t)v;
        } else if (mode == EP_BIAS_RES) {
          const float add = v + bias[col];
          if (fout) fout[idx] = resid[idx] + add;      // final-layer fused output
          else      resid[idx] += add;
        } else {  // EP_BIAS_GELU (exact gelu)
          const float t = v + bias[col];
          outb[idx] = (bf16_t)(0.5f * t * (1.0f + erff(t * 0.70710678118654752f)));
        }
      }
    }
  }
}

// ---------------- LayerNorm: one block per row; vectorized loads (G13) ----------------
template <typename TIN>
__global__ __launch_bounds__(256)
void ln_kern(const TIN* __restrict__ x, const float* __restrict__ g,
             const float* __restrict__ b, bf16_t* __restrict__ y, const int W)
{
  const int row = blockIdx.x;
  const int tid = threadIdx.x;
  const TIN* xr = x + (size_t)row * W;
  float s = 0.f, s2 = 0.f;
  if constexpr (sizeof(TIN) == 4) {
    const f32x4* xv = (const f32x4*)xr;
    for (int i = tid; i < W / 4; i += 256) {
      f32x4 v = xv[i];
#pragma unroll
      for (int e = 0; e < 4; e++) { s += v[e]; s2 += v[e] * v[e]; }
    }
  } else {
    const bf16x8* xv = (const bf16x8*)xr;
    for (int i = tid; i < W / 8; i += 256) {
      bf16x8 v = xv[i];
#pragma unroll
      for (int e = 0; e < 8; e++) { const float f = (float)v[e]; s += f; s2 += f * f; }
    }
  }
#pragma unroll
  for (int off = 32; off > 0; off >>= 1) {
    s  += __shfl_xor(s,  off, 64);
    s2 += __shfl_xor(s2, off, 64);
  }
  __shared__ float red[8];
  if ((tid & 63) == 0) { red[(tid >> 6) * 2] = s; red[(tid >> 6) * 2 + 1] = s2; }
  __syncthreads();
  const float ts  = red[0] + red[2] + red[4] + red[6];
  const float ts2 = red[1] + red[3] + red[5] + red[7];
  const float invW = 1.0f / (float)W;
  const float mean = ts * invW;
  const float var  = fmaxf(ts2 * invW - mean * mean, 0.f);
  const float rs   = rsqrtf(var + 1e-5f);
  bf16_t* yr = y + (size_t)row * W;
  const f32x4* gv = (const f32x4*)g;
  const f32x4* bv = (const f32x4*)b;
  if constexpr (sizeof(TIN) == 4) {
    const f32x4* xv = (const f32x4*)xr;
    bf16x4* yv = (bf16x4*)yr;
    for (int i = tid; i < W / 4; i += 256) {
      f32x4 v = xv[i], gg = gv[i], bb = bv[i];
      bf16x4 o;
#pragma unroll
      for (int e = 0; e < 4; e++) o[e] = (bf16_t)((v[e] - mean) * rs * gg[e] + bb[e]);
      yv[i] = o;
    }
  } else {
    const bf16x8* xv = (const bf16x8*)xr;
    bf16x8* yv = (bf16x8*)yr;
    for (int i = tid; i < W / 8; i += 256) {
      bf16x8 v = xv[i];
      f32x4 g0 = gv[2 * i], g1 = gv[2 * i + 1];
      f32x4 b0 = bv[2 * i], b1 = bv[2 * i + 1];
      bf16x8 o;
#pragma unroll
      for (int e = 0; e < 4; e++) o[e]     = (bf16_t)(((float)v[e]     - mean) * rs * g0[e] + b0[e]);
#pragma unroll
      for (int e = 0; e < 4; e++) o[e + 4] = (bf16_t)(((float)v[e + 4] - mean) * rs * g1[e] + b1[e]);
      yv[i] = o;
    }
  }
}

// ---------------- MFMA flash attention ----------------
// grid (NSEQ/64, NH, NB), 256 threads = 4 waves; T14 async-stage; Pw wave-private.
__global__ __launch_bounds__(256)
void attn_mfma(const bf16_t* __restrict__ qkv, bf16_t* __restrict__ o)
{
  __shared__ __align__(16) bf16_t Ks[64][72];      // K [kv][d], +8 pad
  __shared__ __align__(16) bf16_t Vt[64][72];      // V^T [d][kv], +8 pad
  __shared__ __align__(16) bf16_t Pw[4][16][72];   // per-wave P [q][kv], +8 pad
  const int tid  = threadIdx.x;
  const int lane = tid & 63;
  const int wave = tid >> 6;
  const int quad = lane >> 4;
  const int l15  = lane & 15;
  const int qb = blockIdx.x, hh = blockIdx.y, bb = blockIdx.z;
  const size_t tokbase = (size_t)bb * NSEQ;

  const int qrow = qb * 64 + wave * 16 + l15;
  bf16x8 qf[2];
  {
    const bf16_t* qp = qkv + (tokbase + qrow) * QKVW + hh * DH;
    qf[0] = *(const bf16x8*)(qp + quad * 8);
    qf[1] = *(const bf16x8*)(qp + 32 + quad * 8);
  }

  f32x4 Ot[4];
#pragma unroll
  for (int i = 0; i < 4; i++) Ot[i] = (f32x4){0.f, 0.f, 0.f, 0.f};
  float m_r[4], l_r[4];
#pragma unroll
  for (int r = 0; r < 4; r++) { m_r[r] = -1e30f; l_r[r] = 0.f; }

  const int skv = tid & 63;
  const int sd  = (tid >> 6) * 16;

  bf16x8 k0, k1, v0, v1;
  {
    const bf16_t* kp = qkv + (tokbase + skv) * QKVW + INNERV + hh * DH + sd;
    k0 = *(const bf16x8*)kp;
    k1 = *(const bf16x8*)(kp + 8);
    v0 = *(const bf16x8*)(kp + INNERV);
    v1 = *(const bf16x8*)(kp + INNERV + 8);
  }

  for (int kt = 0; kt < NSEQ / 64; ++kt) {
    __syncthreads();
    *(bf16x8*)&Ks[skv][sd]     = k0;
    *(bf16x8*)&Ks[skv][sd + 8] = k1;
#pragma unroll
    for (int e = 0; e < 8; e++) { Vt[sd + e][skv] = v0[e]; Vt[sd + 8 + e][skv] = v1[e]; }
    __syncthreads();

    // issue next tile's loads NOW — in flight across the whole compute phase (T14)
    bf16x8 nk0 = k0, nk1 = k1, nv0 = v0, nv1 = v1;
    if (kt + 1 < NSEQ / 64) {
      const bf16_t* kp = qkv + (tokbase + (kt + 1) * 64 + skv) * QKVW + INNERV + hh * DH + sd;
      nk0 = *(const bf16x8*)kp;
      nk1 = *(const bf16x8*)(kp + 8);
      nv0 = *(const bf16x8*)(kp + INNERV);
      nv1 = *(const bf16x8*)(kp + INNERV + 8);
    }

    f32x4 st[4];
#pragma unroll
    for (int nt = 0; nt < 4; nt++) {
      bf16x8 b0 = *(const bf16x8*)&Ks[nt * 16 + l15][quad * 8];
      bf16x8 b1 = *(const bf16x8*)&Ks[nt * 16 + l15][32 + quad * 8];
      f32x4 c = (f32x4){0.f, 0.f, 0.f, 0.f};
      c = __builtin_amdgcn_mfma_f32_16x16x32_bf16(qf[0], b0, c, 0, 0, 0);
      c = __builtin_amdgcn_mfma_f32_16x16x32_bf16(qf[1], b1, c, 0, 0, 0);
      st[nt] = c;
    }

    float rmax[4];
#pragma unroll
    for (int r = 0; r < 4; r++) {
      float v = fmaxf(fmaxf(st[0][r], st[1][r]), fmaxf(st[2][r], st[3][r]));
      v = fmaxf(v, __shfl_xor(v, 1, 64));
      v = fmaxf(v, __shfl_xor(v, 2, 64));
      v = fmaxf(v, __shfl_xor(v, 4, 64));
      v = fmaxf(v, __shfl_xor(v, 8, 64));
      rmax[r] = v * 0.125f;
    }
    float alpha[4];
#pragma unroll
    for (int r = 0; r < 4; r++) {
      const float mnew = fmaxf(m_r[r], rmax[r]);
      alpha[r] = __expf(m_r[r] - mnew);
      m_r[r] = mnew;
    }
    float rsum[4] = {0.f, 0.f, 0.f, 0.f};
#pragma unroll
    for (int nt = 0; nt < 4; nt++) {
#pragma unroll
      for (int r = 0; r < 4; r++) {
        const float p = __expf(st[nt][r] * 0.125f - m_r[r]);
        rsum[r] += p;
        Pw[wave][quad * 4 + r][nt * 16 + l15] = (bf16_t)p;
      }
    }
#pragma unroll
    for (int r = 0; r < 4; r++) {
      float v = rsum[r];
      v += __shfl_xor(v, 1, 64);
      v += __shfl_xor(v, 2, 64);
      v += __shfl_xor(v, 4, 64);
      v += __shfl_xor(v, 8, 64);
      l_r[r] = l_r[r] * alpha[r] + v;
    }
#pragma unroll
    for (int dt = 0; dt < 4; dt++)
#pragma unroll
      for (int r = 0; r < 4; r++) Ot[dt][r] *= alpha[r];

    asm volatile("s_waitcnt lgkmcnt(0)" ::: "memory");
    __builtin_amdgcn_sched_barrier(0);

#pragma unroll
    for (int kk = 0; kk < 2; kk++) {
      bf16x8 pa = *(const bf16x8*)&Pw[wave][l15][kk * 32 + quad * 8];
#pragma unroll
      for (int dt = 0; dt < 4; dt++) {
        bf16x8 vb = *(const bf16x8*)&Vt[dt * 16 + l15][kk * 32 + quad * 8];
        Ot[dt] = __builtin_amdgcn_mfma_f32_16x16x32_bf16(pa, vb, Ot[dt], 0, 0, 0);
      }
    }

    k0 = nk0; k1 = nk1; v0 = nv0; v1 = nv1;
  }

  float inv[4];
#pragma unroll
  for (int r = 0; r < 4; r++) inv[r] = 1.0f / l_r[r];
#pragma unroll
  for (int dt = 0; dt < 4; dt++) {
#pragma unroll
    for (int r = 0; r < 4; r++) {
      const int q = qb * 64 + wave * 16 + quad * 4 + r;
      const int d = dt * 16 + l15;
      o[(tokbase + q) * INNERV + hh * DH + d] = (bf16_t)(Ot[dt][r] * inv[r]);
    }
  }
}

// ---------------- ternary quant helpers (f32 weights in), batched x4 ----------------
__global__ __launch_bounds__(64)
void zero_kern(float* __restrict__ p)
{
  p[threadIdx.x] = 0.f;
}

// blockIdx.y selects tensor; grid-stride f32x4 abs-sum into acc[tensor].
__global__ __launch_bounds__(256)
void absmean4_kern(const float* __restrict__ w0, const float* __restrict__ w1,
                   const float* __restrict__ w2, const float* __restrict__ w3,
                   const long n0, const long n1, const long n2, const long n3,
                   float* __restrict__ acc)
{
  const int t = blockIdx.y;
  const float* w = (t == 0) ? w0 : (t == 1) ? w1 : (t == 2) ? w2 : w3;
  const long  n  = (t == 0) ? n0 : (t == 1) ? n1 : (t == 2) ? n2 : n3;
  const int tid = threadIdx.x;
  float s = 0.f;
  const size_t stride = (size_t)256 * gridDim.x * 4;
  for (size_t i = ((size_t)blockIdx.x * 256 + tid) * 4; i < (size_t)n; i += stride) {
    f32x4 v = *(const f32x4*)(w + i);
    s += fabsf(v[0]) + fabsf(v[1]) + fabsf(v[2]) + fabsf(v[3]);
  }
#pragma unroll
  for (int off = 32; off > 0; off >>= 1) s += __shfl_xor(s, off, 64);
  __shared__ float red[4];
  if ((tid & 63) == 0) red[tid >> 6] = s;
  __syncthreads();
  if (tid == 0) atomicAdd(&acc[t], red[0] + red[1] + red[2] + red[3]);
}

// batched ternary quant: wq = clip(round(w/s), -1, 1) as exact bf16 {-1,0,1}.
__global__ __launch_bounds__(256)
void quant4_kern(const float* __restrict__ w0, const float* __restrict__ w1,
                 const float* __restrict__ w2, const float* __restrict__ w3,
                 bf16_t* __restrict__ q0, bf16_t* __restrict__ q1,
                 bf16_t* __restrict__ q2, bf16_t* __restrict__ q3,
                 const int n40, const int n41, const int n42, const int n43,
                 const float* __restrict__ acc,
                 const float inv0, const float inv1, const float inv2, const float inv3)
{
  const int t = blockIdx.y;
  const float* w = (t == 0) ? w0 : (t == 1) ? w1 : (t == 2) ? w2 : w3;
  bf16_t*      q = (t == 0) ? q0 : (t == 1) ? q1 : (t == 2) ? q2 : q3;
  const int   n4 = (t == 0) ? n40 : (t == 1) ? n41 : (t == 2) ? n42 : n43;
  const float iv = (t == 0) ? inv0 : (t == 1) ? inv1 : (t == 2) ? inv2 : inv3;
  const int i = blockIdx.x * 256 + threadIdx.x;
  if (i >= n4) return;
  const float s = acc[t] * iv + 1e-8f;
  f32x4 v = ((const f32x4*)w)[i];
  bf16x4 o;
#pragma unroll
  for (int e = 0; e < 4; e++) {
    float qv = rintf(v[e] / s);  // round-half-even, matches jnp.round
    qv = fminf(1.f, fmaxf(-1.f, qv));
    o[e] = (bf16_t)qv;
  }
  ((bf16x4*)q)[i] = o;
}

// batched plain f32->bf16 cast (last layer)
__global__ __launch_bounds__(256)
void cast4_kern(const float* __restrict__ w0, const float* __restrict__ w1,
                const float* __restrict__ w2, const float* __restrict__ w3,
                bf16_t* __restrict__ q0, bf16_t* __restrict__ q1,
                bf16_t* __restrict__ q2, bf16_t* __restrict__ q3,
                const int n40, const int n41, const int n42, const int n43)
{
  const int t = blockIdx.y;
  const float* w = (t == 0) ? w0 : (t == 1) ? w1 : (t == 2) ? w2 : w3;
  bf16_t*      q = (t == 0) ? q0 : (t == 1) ? q1 : (t == 2) ? q2 : q3;
  const int   n4 = (t == 0) ? n40 : (t == 1) ? n41 : (t == 2) ? n42 : n43;
  const int i = blockIdx.x * 256 + threadIdx.x;
  if (i >= n4) return;
  f32x4 v = ((const f32x4*)w)[i];
  bf16x4 o;
#pragma unroll
  for (int e = 0; e < 4; e++) o[e] = (bf16_t)v[e];
  ((bf16x4*)q)[i] = o;
}

__global__ __launch_bounds__(256)
void copyf_kern(const float* __restrict__ in, float* __restrict__ out, const int n4)
{
  const int i = blockIdx.x * 256 + threadIdx.x;
  if (i < n4) ((f32x4*)out)[i] = ((const f32x4*)in)[i];
}

// ---------------- driver ----------------
extern "C" void kernel_launch(void* const* d_in, const int* in_sizes, int n_in,
                              void* d_out, int out_size, void* d_ws, size_t ws_size,
                              hipStream_t stream)
{
  const float* x     = (const float*)d_in[0];
  const float* ln1_g = (const float*)d_in[1];
  const float* ln1_b = (const float*)d_in[2];
  const float* Wqkv  = (const float*)d_in[3];
  const float* ln2_g = (const float*)d_in[4];
  const float* ln2_b = (const float*)d_in[5];
  const float* Wo    = (const float*)d_in[6];
  const float* bo    = (const float*)d_in[7];
  const float* fg1   = (const float*)d_in[8];
  const float* fb1   = (const float*)d_in[9];
  const float* W1    = (const float*)d_in[10];
  const float* b1    = (const float*)d_in[11];
  const float* fg2   = (const float*)d_in[12];
  const float* fb2   = (const float*)d_in[13];
  const float* W2    = (const float*)d_in[14];
  const float* b2    = (const float*)d_in[15];

  char* ws = (char*)d_ws;
  size_t off = 0;
  float*  sacc  = (float*)(ws + off);  off += 256;                         // scale sums; [63] stays 0
  float*  h     = (float*)(ws + off);  off += (size_t)TOKENS * DIMV * 4;   // 25.2 MB residual stream
  bf16_t* bigA  = (bf16_t*)(ws + off); off += (size_t)TOKENS * MLPW * 2;   // 50.3 MB LN outs / attn out
  bf16_t* bigB  = (bf16_t*)(ws + off); off += (size_t)TOKENS * MLPW * 2;   // 50.3 MB qkv / gelu out
  bf16_t* q_qkv = (bf16_t*)(ws + off); off += (size_t)QKVW * DIMV * 2;
  bf16_t* q_o   = (bf16_t*)(ws + off); off += (size_t)DIMV * INNERV * 2;
  bf16_t* q_1   = (bf16_t*)(ws + off); off += (size_t)MLPW * DIMV * 2;
  bf16_t* q_2   = (bf16_t*)(ws + off); off += (size_t)DIMV * MLPW * 2;     // total ~140 MB

  bf16_t* obuf   = bigA;                              // attn out (12.6 MB)
  bf16_t* ln2out = bigA + (size_t)TOKENS * INNERV;    // LN2 out

  zero_kern<<<1, 64, 0, stream>>>(sacc);
  copyf_kern<<<TOKENS * DIMV / 4 / 256, 256, 0, stream>>>(x, h, TOKENS * DIMV / 4);

  for (int lyr = 0; lyr < 6; ++lyr) {
    const float* wqkv_l = Wqkv + (size_t)lyr * QKVW * DIMV;
    const float* wo_l   = Wo   + (size_t)lyr * DIMV * INNERV;
    const float* w1_l   = W1   + (size_t)lyr * MLPW * DIMV;
    const float* w2_l   = W2   + (size_t)lyr * DIMV * MLPW;
    const float *sq, *so, *s1, *s2p;
    float iq, io, i1, i2, bq, bo2, bb1v, bb2v;
    if (lyr < 5) {
      absmean4_kern<<<dim3(64, 4), 256, 0, stream>>>(
          wqkv_l, wo_l, w1_l, w2_l,
          (long)QKVW * DIMV, (long)DIMV * INNERV, (long)MLPW * DIMV, (long)DIMV * MLPW,
          &sacc[lyr * 4]);
      quant4_kern<<<dim3(MLPW * DIMV / 1024, 4), 256, 0, stream>>>(
          wqkv_l, wo_l, w1_l, w2_l, q_qkv, q_o, q_1, q_2,
          QKVW * DIMV / 4, DIMV * INNERV / 4, MLPW * DIMV / 4, DIMV * MLPW / 4,
          &sacc[lyr * 4],
          1.0f / (QKVW * DIMV), 1.0f / (DIMV * INNERV), 1.0f / (MLPW * DIMV), 1.0f / (DIMV * MLPW));
      sq = &sacc[lyr * 4 + 0]; iq = 1.0f / (QKVW * DIMV); bq = 1e-8f;
      so = &sacc[lyr * 4 + 1]; io = 1.0f / (DIMV * INNERV); bo2 = 1e-8f;
      s1 = &sacc[lyr * 4 + 2]; i1 = 1.0f / (MLPW * DIMV); bb1v = 1e-8f;
      s2p = &sacc[lyr * 4 + 3]; i2 = 1.0f / (DIMV * MLPW); bb2v = 1e-8f;
    } else {
      cast4_kern<<<dim3(MLPW * DIMV / 1024, 4), 256, 0, stream>>>(
          wqkv_l, wo_l, w1_l, w2_l, q_qkv, q_o, q_1, q_2,
          QKVW * DIMV / 4, DIMV * INNERV / 4, MLPW * DIMV / 4, DIMV * MLPW / 4);
      sq = so = s1 = s2p = &sacc[63];  // contains 0
      iq = io = i1 = i2 = 0.f;
      bq = bo2 = bb1v = bb2v = 1.0f;   // s = 0*0 + 1 = 1
    }

    // attention sub-block
    ln_kern<float><<<TOKENS, 256, 0, stream>>>(h, ln1_g + lyr * DIMV, ln1_b + lyr * DIMV, bigA, DIMV);
    gemm_nt<<<dim3(64, QKVW / 128), 256, 0, stream>>>(bigA, q_qkv, DIMV, QKVW, EP_STORE, sq, iq, bq, nullptr, nullptr, bigB, nullptr);
    attn_mfma<<<dim3(NSEQ / 64, NH, NB), 256, 0, stream>>>(bigB, obuf);
    ln_kern<bf16_t><<<TOKENS, 256, 0, stream>>>(obuf, ln2_g + lyr * INNERV, ln2_b + lyr * INNERV, ln2out, INNERV);
    gemm_nt<<<dim3(64, DIMV / 128), 256, 0, stream>>>(ln2out, q_o, INNERV, DIMV, EP_BIAS_RES, so, io, bo2, bo + lyr * DIMV, h, nullptr, nullptr);
    // FF sub-block
    ln_kern<float><<<TOKENS, 256, 0, stream>>>(h, fg1 + lyr * DIMV, fb1 + lyr * DIMV, bigA, DIMV);
    gemm_nt<<<dim3(64, MLPW / 128), 256, 0, stream>>>(bigA, q_1, DIMV, MLPW, EP_BIAS_GELU, s1, i1, bb1v, b1 + lyr * MLPW, nullptr, bigB, nullptr);
    ln_kern<bf16_t><<<TOKENS, 256, 0, stream>>>(bigB, fg2 + lyr * MLPW, fb2 + lyr * MLPW, bigA, MLPW);
    // last layer: fuse the residual add + output write (h + v + bias -> d_out)
    gemm_nt<<<dim3(64, DIMV / 128), 256, 0, stream>>>(bigA, q_2, MLPW, DIMV, EP_BIAS_RES, s2p, i2, bb2v, b2 + lyr * DIMV, h, nullptr,
                                                      (lyr == 5) ? (float*)d_out : nullptr);
  }
}

// Round 6
// 2534.190 us; speedup vs baseline: 1.2706x; 1.0222x over previous
//
#include <hip/hip_runtime.h>
#include <hip/hip_bf16.h>
#include <math.h>

typedef __bf16 bf16_t;
typedef __bf16 bf16x4 __attribute__((ext_vector_type(4)));
typedef __bf16 bf16x8 __attribute__((ext_vector_type(8)));
typedef float  f32x4  __attribute__((ext_vector_type(4)));

#define TOKENS 8192
#define DIMV   768
#define INNERV 768
#define QKVW   2304
#define MLPW   3072
#define NSEQ   1024
#define NB     8
#define NH     12
#define DH     64

enum { EP_STORE = 0, EP_BIAS_RES = 1, EP_BIAS_GELU = 2 };

// async global->LDS DMA, 16B per lane. LDS dest must be wave-uniform base + lane*16.
__device__ __forceinline__ void gload_lds16(const bf16_t* g, bf16_t* l)
{
  __builtin_amdgcn_global_load_lds((const __attribute__((address_space(1))) void*)g,
                                   (__attribute__((address_space(3))) void*)l,
                                   16, 0, 0);
}

// ---------------- GEMM: C[M,N] = s * (A[M,K] * B[N,K]^T) + bias, bf16 in, f32 acc ----
// 128x128 tile, BK=32, double-buffered LDS, counted-vmcnt pipeline (T4) +
// T2 bank-conflict swizzle (rule #21 both-sides): LDS dest LINEAR (gload_lds
// requirement); global source col-slot XOR'd by f(row)=(row>>1)&3; fragment reads
// XOR the same f.
__global__ __launch_bounds__(256)
void gemm_nt(const bf16_t* __restrict__ A, const bf16_t* __restrict__ B,
             const int K, const int N, const int mode,
             const float* __restrict__ sacc_p, const float sinvn, const float sbias,
             const float* __restrict__ bias,
             float* __restrict__ resid,
             bf16_t* __restrict__ outb,
             float* __restrict__ fout)   // if non-null (EP_BIAS_RES): fout = resid + v + bias
{
  __shared__ __align__(16) bf16_t lsA[2][128 * 32];
  __shared__ __align__(16) bf16_t lsB[2][128 * 32];
  const int tid  = threadIdx.x;
  const int lane = tid & 63;
  const int wave = tid >> 6;
  const int wm = wave >> 1, wn = wave & 1;
  const int bm = blockIdx.x, bn = blockIdx.y;

  const int srow = wave * 32 + (lane >> 2);
  const int fsw  = (srow >> 1) & 3;                  // source-swizzle (same for srow+16)
  const int scol = ((lane & 3) ^ fsw) * 8;           // pre-swizzled GLOBAL col
  const bf16_t* gA = A + (size_t)(bm * 128 + srow) * K + scol;
  const bf16_t* gB = B + (size_t)(bn * 128 + srow) * K + scol;
  const int l0 = srow * 32 + (lane & 3) * 8;         // LINEAR LDS dest
  const int l1 = (srow + 16) * 32 + (lane & 3) * 8;

  f32x4 acc[4][4];
#pragma unroll
  for (int i = 0; i < 4; i++)
#pragma unroll
    for (int j = 0; j < 4; j++) acc[i][j] = (f32x4){0.f, 0.f, 0.f, 0.f};

  const int fr   = ((lane & 15) >> 1) & 3;
  const int rsl  = ((lane >> 4) ^ fr) * 8;
  const int arow = (wm * 64 + (lane & 15)) * 32 + rsl;
  const int brow = (wn * 64 + (lane & 15)) * 32 + rsl;

  auto stage = [&](int b, int kb) {
    gload_lds16(gA + kb,                  &lsA[b][l0]);
    gload_lds16(gA + (size_t)16 * K + kb, &lsA[b][l1]);
    gload_lds16(gB + kb,                  &lsB[b][l0]);
    gload_lds16(gB + (size_t)16 * K + kb, &lsB[b][l1]);
  };
  auto compute = [&](int b) {
    bf16x8 af[4], bfv[4];
#pragma unroll
    for (int i = 0; i < 4; i++) af[i]  = *(const bf16x8*)&lsA[b][arow + i * 16 * 32];
#pragma unroll
    for (int j = 0; j < 4; j++) bfv[j] = *(const bf16x8*)&lsB[b][brow + j * 16 * 32];
#pragma unroll
    for (int i = 0; i < 4; i++)
#pragma unroll
      for (int j = 0; j < 4; j++)
        acc[i][j] = __builtin_amdgcn_mfma_f32_16x16x32_bf16(af[i], bfv[j], acc[i][j], 0, 0, 0);
  };

  const int NT = K / 32;
  stage(0, 0);
  stage(1, 32);
  int cur = 0;
  for (int t = 0; t < NT - 1; ++t) {
    asm volatile("s_waitcnt vmcnt(4)" ::: "memory");   // tile t landed; t+1 in flight
    __builtin_amdgcn_s_barrier();
    __builtin_amdgcn_sched_barrier(0);
    compute(cur);
    asm volatile("s_waitcnt lgkmcnt(0)" ::: "memory");
    __builtin_amdgcn_s_barrier();                      // all waves done reading buf[cur]
    __builtin_amdgcn_sched_barrier(0);
    if (t + 2 < NT) stage(cur, (t + 2) * 32);
    cur ^= 1;
  }
  asm volatile("s_waitcnt vmcnt(0)" ::: "memory");
  __builtin_amdgcn_s_barrier();
  __builtin_amdgcn_sched_barrier(0);
  compute(cur);

  const float s = (*sacc_p) * sinvn + sbias;
  const int r0 = bm * 128 + wm * 64 + (lane >> 4) * 4;
  const int c0 = bn * 128 + wn * 64 + (lane & 15);
#pragma unroll
  for (int i = 0; i < 4; i++) {
#pragma unroll
    for (int j = 0; j < 4; j++) {
      const int col = c0 + j * 16;
#pragma unroll
      for (int r = 0; r < 4; r++) {
        const int row = r0 + i * 16 + r;
        const float v = acc[i][j][r] * s;
        const size_t idx = (size_t)row * N + col;
        if (mode == EP_STORE) {
          outb[idx] = (bf16_t)v;
        } else if (mode == EP_BIAS_RES) {
          const float add = v + bias[col];
          if (fout) fout[idx] = resid[idx] + add;      // final-layer fused output
          else      resid[idx] += add;
        } else {  // EP_BIAS_GELU (exact gelu)
          const float t = v + bias[col];
          outb[idx] = (bf16_t)(0.5f * t * (1.0f + erff(t * 0.70710678118654752f)));
        }
      }
    }
  }
}

// ---------------- LayerNorm: one block per row; vectorized loads (G13) ----------------
template <typename TIN>
__global__ __launch_bounds__(256)
void ln_kern(const TIN* __restrict__ x, const float* __restrict__ g,
             const float* __restrict__ b, bf16_t* __restrict__ y, const int W)
{
  const int row = blockIdx.x;
  const int tid = threadIdx.x;
  const TIN* xr = x + (size_t)row * W;
  float s = 0.f, s2 = 0.f;
  if constexpr (sizeof(TIN) == 4) {
    const f32x4* xv = (const f32x4*)xr;
    for (int i = tid; i < W / 4; i += 256) {
      f32x4 v = xv[i];
#pragma unroll
      for (int e = 0; e < 4; e++) { s += v[e]; s2 += v[e] * v[e]; }
    }
  } else {
    const bf16x8* xv = (const bf16x8*)xr;
    for (int i = tid; i < W / 8; i += 256) {
      bf16x8 v = xv[i];
#pragma unroll
      for (int e = 0; e < 8; e++) { const float f = (float)v[e]; s += f; s2 += f * f; }
    }
  }
#pragma unroll
  for (int off = 32; off > 0; off >>= 1) {
    s  += __shfl_xor(s,  off, 64);
    s2 += __shfl_xor(s2, off, 64);
  }
  __shared__ float red[8];
  if ((tid & 63) == 0) { red[(tid >> 6) * 2] = s; red[(tid >> 6) * 2 + 1] = s2; }
  __syncthreads();
  const float ts  = red[0] + red[2] + red[4] + red[6];
  const float ts2 = red[1] + red[3] + red[5] + red[7];
  const float invW = 1.0f / (float)W;
  const float mean = ts * invW;
  const float var  = fmaxf(ts2 * invW - mean * mean, 0.f);
  const float rs   = rsqrtf(var + 1e-5f);
  bf16_t* yr = y + (size_t)row * W;
  const f32x4* gv = (const f32x4*)g;
  const f32x4* bv = (const f32x4*)b;
  if constexpr (sizeof(TIN) == 4) {
    const f32x4* xv = (const f32x4*)xr;
    bf16x4* yv = (bf16x4*)yr;
    for (int i = tid; i < W / 4; i += 256) {
      f32x4 v = xv[i], gg = gv[i], bb = bv[i];
      bf16x4 o;
#pragma unroll
      for (int e = 0; e < 4; e++) o[e] = (bf16_t)((v[e] - mean) * rs * gg[e] + bb[e]);
      yv[i] = o;
    }
  } else {
    const bf16x8* xv = (const bf16x8*)xr;
    bf16x8* yv = (bf16x8*)yr;
    for (int i = tid; i < W / 8; i += 256) {
      bf16x8 v = xv[i];
      f32x4 g0 = gv[2 * i], g1 = gv[2 * i + 1];
      f32x4 b0 = bv[2 * i], b1 = bv[2 * i + 1];
      bf16x8 o;
#pragma unroll
      for (int e = 0; e < 4; e++) o[e]     = (bf16_t)(((float)v[e]     - mean) * rs * g0[e] + b0[e]);
#pragma unroll
      for (int e = 0; e < 4; e++) o[e + 4] = (bf16_t)(((float)v[e + 4] - mean) * rs * g1[e] + b1[e]);
      yv[i] = o;
    }
  }
}

// ---------------- MFMA flash attention ----------------
// grid (NSEQ/64, NH, NB), 256 threads = 4 waves; T14 async-stage; Pw wave-private.
// Softmax in log2 domain: m2 tracks max(S)*0.125*log2e; p = exp2(fma(S,SCL,-m2)).
// T13 defer-max (THR=8 log2 => P<=256). Denominator kept LANE-PARTIAL (lp),
// reduced once at the end — removes 16 cross-lane ops per tile.
__global__ __launch_bounds__(256)
void attn_mfma(const bf16_t* __restrict__ qkv, bf16_t* __restrict__ o)
{
  __shared__ __align__(16) bf16_t Ks[64][72];      // K [kv][d], +8 pad
  __shared__ __align__(16) bf16_t Vt[64][72];      // V^T [d][kv], +8 pad
  __shared__ __align__(16) bf16_t Pw[4][16][72];   // per-wave P [q][kv], +8 pad
  const float SCL = 0.125f * 1.44269504088896f;    // scale * log2(e)
  const int tid  = threadIdx.x;
  const int lane = tid & 63;
  const int wave = tid >> 6;
  const int quad = lane >> 4;
  const int l15  = lane & 15;
  const int qb = blockIdx.x, hh = blockIdx.y, bb = blockIdx.z;
  const size_t tokbase = (size_t)bb * NSEQ;

  const int qrow = qb * 64 + wave * 16 + l15;
  bf16x8 qf[2];
  {
    const bf16_t* qp = qkv + (tokbase + qrow) * QKVW + hh * DH;
    qf[0] = *(const bf16x8*)(qp + quad * 8);
    qf[1] = *(const bf16x8*)(qp + 32 + quad * 8);
  }

  f32x4 Ot[4];
#pragma unroll
  for (int i = 0; i < 4; i++) Ot[i] = (f32x4){0.f, 0.f, 0.f, 0.f};
  float m2[4], lp[4];                // m in log2 units; lp = lane-partial denom
#pragma unroll
  for (int r = 0; r < 4; r++) { m2[r] = -1e30f; lp[r] = 0.f; }

  const int skv = tid & 63;
  const int sd  = (tid >> 6) * 16;

  bf16x8 k0, k1, v0, v1;
  {
    const bf16_t* kp = qkv + (tokbase + skv) * QKVW + INNERV + hh * DH + sd;
    k0 = *(const bf16x8*)kp;
    k1 = *(const bf16x8*)(kp + 8);
    v0 = *(const bf16x8*)(kp + INNERV);
    v1 = *(const bf16x8*)(kp + INNERV + 8);
  }

  for (int kt = 0; kt < NSEQ / 64; ++kt) {
    __syncthreads();
    *(bf16x8*)&Ks[skv][sd]     = k0;
    *(bf16x8*)&Ks[skv][sd + 8] = k1;
#pragma unroll
    for (int e = 0; e < 8; e++) { Vt[sd + e][skv] = v0[e]; Vt[sd + 8 + e][skv] = v1[e]; }
    __syncthreads();

    // issue next tile's loads NOW — in flight across the whole compute phase (T14)
    bf16x8 nk0 = k0, nk1 = k1, nv0 = v0, nv1 = v1;
    if (kt + 1 < NSEQ / 64) {
      const bf16_t* kp = qkv + (tokbase + (kt + 1) * 64 + skv) * QKVW + INNERV + hh * DH + sd;
      nk0 = *(const bf16x8*)kp;
      nk1 = *(const bf16x8*)(kp + 8);
      nv0 = *(const bf16x8*)(kp + INNERV);
      nv1 = *(const bf16x8*)(kp + INNERV + 8);
    }

    f32x4 st[4];
    __builtin_amdgcn_s_setprio(1);
#pragma unroll
    for (int nt = 0; nt < 4; nt++) {
      bf16x8 b0 = *(const bf16x8*)&Ks[nt * 16 + l15][quad * 8];
      bf16x8 b1 = *(const bf16x8*)&Ks[nt * 16 + l15][32 + quad * 8];
      f32x4 c = (f32x4){0.f, 0.f, 0.f, 0.f};
      c = __builtin_amdgcn_mfma_f32_16x16x32_bf16(qf[0], b0, c, 0, 0, 0);
      c = __builtin_amdgcn_mfma_f32_16x16x32_bf16(qf[1], b1, c, 0, 0, 0);
      st[nt] = c;
    }
    __builtin_amdgcn_s_setprio(0);

    // row max in log2 units (reduce across l15 lanes)
    float rmax2[4];
#pragma unroll
    for (int r = 0; r < 4; r++) {
      float v = fmaxf(fmaxf(st[0][r], st[1][r]), fmaxf(st[2][r], st[3][r]));
      v = fmaxf(v, __shfl_xor(v, 1, 64));
      v = fmaxf(v, __shfl_xor(v, 2, 64));
      v = fmaxf(v, __shfl_xor(v, 4, 64));
      v = fmaxf(v, __shfl_xor(v, 8, 64));
      rmax2[r] = v * SCL;
    }
    // T13 defer-max: rescale only if some row grew past THR=8 (log2) => P <= 256
    const bool ok = (rmax2[0] <= m2[0] + 8.f) && (rmax2[1] <= m2[1] + 8.f) &&
                    (rmax2[2] <= m2[2] + 8.f) && (rmax2[3] <= m2[3] + 8.f);
    if (!__all(ok)) {
#pragma unroll
      for (int r = 0; r < 4; r++) {
        const float mnew = fmaxf(m2[r], rmax2[r]);
        const float alpha = exp2f(m2[r] - mnew);
        m2[r] = mnew;
        lp[r] *= alpha;
#pragma unroll
        for (int dt = 0; dt < 4; dt++) Ot[dt][r] *= alpha;
      }
    }
    // P = exp2(S*SCL - m2): 1 fma + 1 v_exp per element; accumulate lane-partial denom
#pragma unroll
    for (int nt = 0; nt < 4; nt++) {
#pragma unroll
      for (int r = 0; r < 4; r++) {
        const float p = exp2f(fmaf(st[nt][r], SCL, -m2[r]));
        lp[r] += p;
        Pw[wave][quad * 4 + r][nt * 16 + l15] = (bf16_t)p;
      }
    }

    asm volatile("s_waitcnt lgkmcnt(0)" ::: "memory");
    __builtin_amdgcn_sched_barrier(0);

    __builtin_amdgcn_s_setprio(1);
#pragma unroll
    for (int kk = 0; kk < 2; kk++) {
      bf16x8 pa = *(const bf16x8*)&Pw[wave][l15][kk * 32 + quad * 8];
#pragma unroll
      for (int dt = 0; dt < 4; dt++) {
        bf16x8 vb = *(const bf16x8*)&Vt[dt * 16 + l15][kk * 32 + quad * 8];
        Ot[dt] = __builtin_amdgcn_mfma_f32_16x16x32_bf16(pa, vb, Ot[dt], 0, 0, 0);
      }
    }
    __builtin_amdgcn_s_setprio(0);

    k0 = nk0; k1 = nk1; v0 = nv0; v1 = nv1;
  }

  // final denominator reduce (once, not per tile)
  float inv[4];
#pragma unroll
  for (int r = 0; r < 4; r++) {
    float v = lp[r];
    v += __shfl_xor(v, 1, 64);
    v += __shfl_xor(v, 2, 64);
    v += __shfl_xor(v, 4, 64);
    v += __shfl_xor(v, 8, 64);
    inv[r] = 1.0f / v;
  }
#pragma unroll
  for (int dt = 0; dt < 4; dt++) {
#pragma unroll
    for (int r = 0; r < 4; r++) {
      const int q = qb * 64 + wave * 16 + quad * 4 + r;
      const int d = dt * 16 + l15;
      o[(tokbase + q) * INNERV + hh * DH + d] = (bf16_t)(Ot[dt][r] * inv[r]);
    }
  }
}

// ---------------- ternary quant helpers (f32 weights in), batched x4 ----------------
__global__ __launch_bounds__(64)
void zero_kern(float* __restrict__ p)
{
  p[threadIdx.x] = 0.f;
}

__global__ __launch_bounds__(256)
void absmean4_kern(const float* __restrict__ w0, const float* __restrict__ w1,
                   const float* __restrict__ w2, const float* __restrict__ w3,
                   const long n0, const long n1, const long n2, const long n3,
                   float* __restrict__ acc)
{
  const int t = blockIdx.y;
  const float* w = (t == 0) ? w0 : (t == 1) ? w1 : (t == 2) ? w2 : w3;
  const long  n  = (t == 0) ? n0 : (t == 1) ? n1 : (t == 2) ? n2 : n3;
  const int tid = threadIdx.x;
  float s = 0.f;
  const size_t stride = (size_t)256 * gridDim.x * 4;
  for (size_t i = ((size_t)blockIdx.x * 256 + tid) * 4; i < (size_t)n; i += stride) {
    f32x4 v = *(const f32x4*)(w + i);
    s += fabsf(v[0]) + fabsf(v[1]) + fabsf(v[2]) + fabsf(v[3]);
  }
#pragma unroll
  for (int off = 32; off > 0; off >>= 1) s += __shfl_xor(s, off, 64);
  __shared__ float red[4];
  if ((tid & 63) == 0) red[tid >> 6] = s;
  __syncthreads();
  if (tid == 0) atomicAdd(&acc[t], red[0] + red[1] + red[2] + red[3]);
}

__global__ __launch_bounds__(256)
void quant4_kern(const float* __restrict__ w0, const float* __restrict__ w1,
                 const float* __restrict__ w2, const float* __restrict__ w3,
                 bf16_t* __restrict__ q0, bf16_t* __restrict__ q1,
                 bf16_t* __restrict__ q2, bf16_t* __restrict__ q3,
                 const int n40, const int n41, const int n42, const int n43,
                 const float* __restrict__ acc,
                 const float inv0, const float inv1, const float inv2, const float inv3)
{
  const int t = blockIdx.y;
  const float* w = (t == 0) ? w0 : (t == 1) ? w1 : (t == 2) ? w2 : w3;
  bf16_t*      q = (t == 0) ? q0 : (t == 1) ? q1 : (t == 2) ? q2 : q3;
  const int   n4 = (t == 0) ? n40 : (t == 1) ? n41 : (t == 2) ? n42 : n43;
  const float iv = (t == 0) ? inv0 : (t == 1) ? inv1 : (t == 2) ? inv2 : inv3;
  const int i = blockIdx.x * 256 + threadIdx.x;
  if (i >= n4) return;
  const float s = acc[t] * iv + 1e-8f;
  f32x4 v = ((const f32x4*)w)[i];
  bf16x4 o;
#pragma unroll
  for (int e = 0; e < 4; e++) {
    float qv = rintf(v[e] / s);  // round-half-even, matches jnp.round
    qv = fminf(1.f, fmaxf(-1.f, qv));
    o[e] = (bf16_t)qv;
  }
  ((bf16x4*)q)[i] = o;
}

__global__ __launch_bounds__(256)
void cast4_kern(const float* __restrict__ w0, const float* __restrict__ w1,
                const float* __restrict__ w2, const float* __restrict__ w3,
                bf16_t* __restrict__ q0, bf16_t* __restrict__ q1,
                bf16_t* __restrict__ q2, bf16_t* __restrict__ q3,
                const int n40, const int n41, const int n42, const int n43)
{
  const int t = blockIdx.y;
  const float* w = (t == 0) ? w0 : (t == 1) ? w1 : (t == 2) ? w2 : w3;
  bf16_t*      q = (t == 0) ? q0 : (t == 1) ? q1 : (t == 2) ? q2 : q3;
  const int   n4 = (t == 0) ? n40 : (t == 1) ? n41 : (t == 2) ? n42 : n43;
  const int i = blockIdx.x * 256 + threadIdx.x;
  if (i >= n4) return;
  f32x4 v = ((const f32x4*)w)[i];
  bf16x4 o;
#pragma unroll
  for (int e = 0; e < 4; e++) o[e] = (bf16_t)v[e];
  ((bf16x4*)q)[i] = o;
}

__global__ __launch_bounds__(256)
void copyf_kern(const float* __restrict__ in, float* __restrict__ out, const int n4)
{
  const int i = blockIdx.x * 256 + threadIdx.x;
  if (i < n4) ((f32x4*)out)[i] = ((const f32x4*)in)[i];
}

// ---------------- driver ----------------
extern "C" void kernel_launch(void* const* d_in, const int* in_sizes, int n_in,
                              void* d_out, int out_size, void* d_ws, size_t ws_size,
                              hipStream_t stream)
{
  const float* x     = (const float*)d_in[0];
  const float* ln1_g = (const float*)d_in[1];
  const float* ln1_b = (const float*)d_in[2];
  const float* Wqkv  = (const float*)d_in[3];
  const float* ln2_g = (const float*)d_in[4];
  const float* ln2_b = (const float*)d_in[5];
  const float* Wo    = (const float*)d_in[6];
  const float* bo    = (const float*)d_in[7];
  const float* fg1   = (const float*)d_in[8];
  const float* fb1   = (const float*)d_in[9];
  const float* W1    = (const float*)d_in[10];
  const float* b1    = (const float*)d_in[11];
  const float* fg2   = (const float*)d_in[12];
  const float* fb2   = (const float*)d_in[13];
  const float* W2    = (const float*)d_in[14];
  const float* b2    = (const float*)d_in[15];

  char* ws = (char*)d_ws;
  size_t off = 0;
  float*  sacc  = (float*)(ws + off);  off += 256;                         // scale sums; [63] stays 0
  float*  h     = (float*)(ws + off);  off += (size_t)TOKENS * DIMV * 4;   // 25.2 MB residual stream
  bf16_t* bigA  = (bf16_t*)(ws + off); off += (size_t)TOKENS * MLPW * 2;   // 50.3 MB LN outs / attn out
  bf16_t* bigB  = (bf16_t*)(ws + off); off += (size_t)TOKENS * MLPW * 2;   // 50.3 MB qkv / gelu out
  bf16_t* q_qkv = (bf16_t*)(ws + off); off += (size_t)QKVW * DIMV * 2;
  bf16_t* q_o   = (bf16_t*)(ws + off); off += (size_t)DIMV * INNERV * 2;
  bf16_t* q_1   = (bf16_t*)(ws + off); off += (size_t)MLPW * DIMV * 2;
  bf16_t* q_2   = (bf16_t*)(ws + off); off += (size_t)DIMV * MLPW * 2;     // total ~140 MB

  bf16_t* obuf   = bigA;                              // attn out (12.6 MB)
  bf16_t* ln2out = bigA + (size_t)TOKENS * INNERV;    // LN2 out

  zero_kern<<<1, 64, 0, stream>>>(sacc);
  copyf_kern<<<TOKENS * DIMV / 4 / 256, 256, 0, stream>>>(x, h, TOKENS * DIMV / 4);

  for (int lyr = 0; lyr < 6; ++lyr) {
    const float* wqkv_l = Wqkv + (size_t)lyr * QKVW * DIMV;
    const float* wo_l   = Wo   + (size_t)lyr * DIMV * INNERV;
    const float* w1_l   = W1   + (size_t)lyr * MLPW * DIMV;
    const float* w2_l   = W2   + (size_t)lyr * DIMV * MLPW;
    const float *sq, *so, *s1, *s2p;
    float iq, io, i1, i2, bq, bo2, bb1v, bb2v;
    if (lyr < 5) {
      absmean4_kern<<<dim3(64, 4), 256, 0, stream>>>(
          wqkv_l, wo_l, w1_l, w2_l,
          (long)QKVW * DIMV, (long)DIMV * INNERV, (long)MLPW * DIMV, (long)DIMV * MLPW,
          &sacc[lyr * 4]);
      quant4_kern<<<dim3(MLPW * DIMV / 1024, 4), 256, 0, stream>>>(
          wqkv_l, wo_l, w1_l, w2_l, q_qkv, q_o, q_1, q_2,
          QKVW * DIMV / 4, DIMV * INNERV / 4, MLPW * DIMV / 4, DIMV * MLPW / 4,
          &sacc[lyr * 4],
          1.0f / (QKVW * DIMV), 1.0f / (DIMV * INNERV), 1.0f / (MLPW * DIMV), 1.0f / (DIMV * MLPW));
      sq = &sacc[lyr * 4 + 0]; iq = 1.0f / (QKVW * DIMV); bq = 1e-8f;
      so = &sacc[lyr * 4 + 1]; io = 1.0f / (DIMV * INNERV); bo2 = 1e-8f;
      s1 = &sacc[lyr * 4 + 2]; i1 = 1.0f / (MLPW * DIMV); bb1v = 1e-8f;
      s2p = &sacc[lyr * 4 + 3]; i2 = 1.0f / (DIMV * MLPW); bb2v = 1e-8f;
    } else {
      cast4_kern<<<dim3(MLPW * DIMV / 1024, 4), 256, 0, stream>>>(
          wqkv_l, wo_l, w1_l, w2_l, q_qkv, q_o, q_1, q_2,
          QKVW * DIMV / 4, DIMV * INNERV / 4, MLPW * DIMV / 4, DIMV * MLPW / 4);
      sq = so = s1 = s2p = &sacc[63];  // contains 0
      iq = io = i1 = i2 = 0.f;
      bq = bo2 = bb1v = bb2v = 1.0f;   // s = 0*0 + 1 = 1
    }

    // attention sub-block
    ln_kern<float><<<TOKENS, 256, 0, stream>>>(h, ln1_g + lyr * DIMV, ln1_b + lyr * DIMV, bigA, DIMV);
    gemm_nt<<<dim3(64, QKVW / 128), 256, 0, stream>>>(bigA, q_qkv, DIMV, QKVW, EP_STORE, sq, iq, bq, nullptr, nullptr, bigB, nullptr);
    attn_mfma<<<dim3(NSEQ / 64, NH, NB), 256, 0, stream>>>(bigB, obuf);
    ln_kern<bf16_t><<<TOKENS, 256, 0, stream>>>(obuf, ln2_g + lyr * INNERV, ln2_b + lyr * INNERV, ln2out, INNERV);
    gemm_nt<<<dim3(64, DIMV / 128), 256, 0, stream>>>(ln2out, q_o, INNERV, DIMV, EP_BIAS_RES, so, io, bo2, bo + lyr * DIMV, h, nullptr, nullptr);
    // FF sub-block
    ln_kern<float><<<TOKENS, 256, 0, stream>>>(h, fg1 + lyr * DIMV, fb1 + lyr * DIMV, bigA, DIMV);
    gemm_nt<<<dim3(64, MLPW / 128), 256, 0, stream>>>(bigA, q_1, DIMV, MLPW, EP_BIAS_GELU, s1, i1, bb1v, b1 + lyr * MLPW, nullptr, bigB, nullptr);
    ln_kern<bf16_t><<<TOKENS, 256, 0, stream>>>(bigB, fg2 + lyr * MLPW, fb2 + lyr * MLPW, bigA, MLPW);
    // last layer: fuse the residual add + output write (h + v + bias -> d_out)
    gemm_nt<<<dim3(64, DIMV / 128), 256, 0, stream>>>(bigA, q_2, MLPW, DIMV, EP_BIAS_RES, s2p, i2, bb2v, b2 + lyr * DIMV, h, nullptr,
                                                      (lyr == 5) ? (float*)d_out : nullptr);
  }
}

// Round 7
// 2407.543 us; speedup vs baseline: 1.3374x; 1.0526x over previous
//
#include <hip/hip_runtime.h>
#include <hip/hip_bf16.h>
#include <math.h>

typedef __bf16 bf16_t;
typedef __bf16 bf16x4 __attribute__((ext_vector_type(4)));
typedef __bf16 bf16x8 __attribute__((ext_vector_type(8)));
typedef float  f32x4  __attribute__((ext_vector_type(4)));

#define TOKENS 8192
#define DIMV   768
#define INNERV 768
#define QKVW   2304
#define MLPW   3072
#define NSEQ   1024
#define NB     8
#define NH     12
#define DH     64

enum { EP_STORE = 0, EP_BIAS_RES = 1, EP_BIAS_GELU = 2 };

// async global->LDS DMA, 16B per lane. LDS dest must be wave-uniform base + lane*16.
__device__ __forceinline__ void gload_lds16(const bf16_t* g, bf16_t* l)
{
  __builtin_amdgcn_global_load_lds((const __attribute__((address_space(1))) void*)g,
                                   (__attribute__((address_space(3))) void*)l,
                                   16, 0, 0);
}

// exact-to-1.5e-7 gelu via A&S 7.1.26 erf (bit-identical after bf16 vs erff path,
// ~14 VALU ops vs libm erff's ~30 with branches).
__device__ __forceinline__ float gelu_fast(float x)
{
  const float z = fabsf(x) * 0.70710678118654752f;
  const float d = fmaf(0.3275911f, z, 1.0f);
#if __has_builtin(__builtin_amdgcn_rcpf)
  const float t = __builtin_amdgcn_rcpf(d);
#else
  const float t = 1.0f / d;
#endif
  float p = fmaf(t, 1.061405429f, -1.453152027f);
  p = fmaf(t, p, 1.421413741f);
  p = fmaf(t, p, -0.284496736f);
  p = fmaf(t, p, 0.254829592f);
  p = t * p;
  const float e = __expf(-z * z);
  float erfv = fmaf(-p, e, 1.0f);              // erf(|x|/sqrt(2)), >=0
  erfv = copysignf(erfv, x);
  return 0.5f * x * (1.0f + erfv);
}

// ---------------- GEMM: C[M,N] = s * (A[M,K] * B[N,K]^T) + bias, bf16 in, f32 acc ----
// BMx128 tile (BM=128 or 64), BK=32, double-buffered LDS, counted-vmcnt pipeline (T4)
// + T2 swizzle (both-sides, rule #21): LDS linear, global source col-slot XOR'd by
// f(row)=(row>>1)&3, fragment reads XOR the same f (f invariant under row+16/+32).
// BM=64 halves the block so N=768 GEMMs get 768 blocks = 3/CU (latency hiding via TLP).
template <int BM>
__global__ __launch_bounds__(256)
void gemm_nt(const bf16_t* __restrict__ A, const bf16_t* __restrict__ B,
             const int K, const int N, const int mode,
             const float* __restrict__ sacc_p, const float sinvn, const float sbias,
             const float* __restrict__ bias,
             float* __restrict__ resid,
             bf16_t* __restrict__ outb,
             float* __restrict__ fout)   // if non-null (EP_BIAS_RES): fout = resid + v + bias
{
  constexpr int MI = BM / 32;            // acc rows of 16x16 frags per wave (4 or 2)
  constexpr int WR = BM / 2;             // wave-tile rows
  __shared__ __align__(16) bf16_t lsA[2][BM * 32];
  __shared__ __align__(16) bf16_t lsB[2][128 * 32];
  const int tid  = threadIdx.x;
  const int lane = tid & 63;
  const int wave = tid >> 6;
  const int wm = wave >> 1, wn = wave & 1;
  const int bm = blockIdx.x, bn = blockIdx.y;

  // B staging: wave w stages rows [w*32, w*32+32), 2 loads of 16B/lane, LDS linear.
  const int srB   = wave * 32 + (lane >> 2);
  const int fswB  = (srB >> 1) & 3;
  const int scolB = ((lane & 3) ^ fswB) * 8;
  const bf16_t* gB = B + (size_t)(bn * 128 + srB) * K + scolB;
  const int lb0 = srB * 32 + (lane & 3) * 8;
  const int lb1 = (srB + 16) * 32 + (lane & 3) * 8;

  // A staging: BM=128 like B (2 loads); BM=64: rows [w*16, w*16+16), 1 load.
  const int srA   = (BM == 128) ? srB : (wave * 16 + (lane >> 2));
  const int fswA  = (srA >> 1) & 3;
  const int scolA = ((lane & 3) ^ fswA) * 8;
  const bf16_t* gA = A + (size_t)(bm * BM + srA) * K + scolA;
  const int la0 = srA * 32 + (lane & 3) * 8;
  const int la1 = (srA + 16) * 32 + (lane & 3) * 8;   // BM==128 only

  f32x4 acc[MI][4];
#pragma unroll
  for (int i = 0; i < MI; i++)
#pragma unroll
    for (int j = 0; j < 4; j++) acc[i][j] = (f32x4){0.f, 0.f, 0.f, 0.f};

  // fragment reads: row = wm*WR + l15 (+i*16); col-slot = quad ^ f(row);
  // f(row) = (l15>>1)&3 since WR,16 contribute 0 to (row>>1)&3.
  const int fr   = ((lane & 15) >> 1) & 3;
  const int rsl  = ((lane >> 4) ^ fr) * 8;
  const int arow = (wm * WR + (lane & 15)) * 32 + rsl;
  const int brow = (wn * 64 + (lane & 15)) * 32 + rsl;

  auto stage = [&](int b, int kb) {
    gload_lds16(gA + kb, &lsA[b][la0]);
    if constexpr (BM == 128) gload_lds16(gA + (size_t)16 * K + kb, &lsA[b][la1]);
    gload_lds16(gB + kb, &lsB[b][lb0]);
    gload_lds16(gB + (size_t)16 * K + kb, &lsB[b][lb1]);
  };
  auto compute = [&](int b) {
    bf16x8 af[MI], bfv[4];
#pragma unroll
    for (int i = 0; i < MI; i++) af[i]  = *(const bf16x8*)&lsA[b][arow + i * 16 * 32];
#pragma unroll
    for (int j = 0; j < 4; j++)  bfv[j] = *(const bf16x8*)&lsB[b][brow + j * 16 * 32];
#pragma unroll
    for (int i = 0; i < MI; i++)
#pragma unroll
      for (int j = 0; j < 4; j++)
        acc[i][j] = __builtin_amdgcn_mfma_f32_16x16x32_bf16(af[i], bfv[j], acc[i][j], 0, 0, 0);
  };

  const int NT = K / 32;
  stage(0, 0);
  stage(1, 32);
  int cur = 0;
  for (int t = 0; t < NT - 1; ++t) {
    // wait tile t (this wave's own loads: 4 for BM=128, 3 for BM=64); t+1 in flight
    if constexpr (BM == 128) asm volatile("s_waitcnt vmcnt(4)" ::: "memory");
    else                     asm volatile("s_waitcnt vmcnt(3)" ::: "memory");
    __builtin_amdgcn_s_barrier();
    __builtin_amdgcn_sched_barrier(0);
    compute(cur);
    asm volatile("s_waitcnt lgkmcnt(0)" ::: "memory");
    __builtin_amdgcn_s_barrier();                      // all waves done reading buf[cur]
    __builtin_amdgcn_sched_barrier(0);
    if (t + 2 < NT) stage(cur, (t + 2) * 32);
    cur ^= 1;
  }
  asm volatile("s_waitcnt vmcnt(0)" ::: "memory");
  __builtin_amdgcn_s_barrier();
  __builtin_amdgcn_sched_barrier(0);
  compute(cur);

  const float s = (*sacc_p) * sinvn + sbias;
  const int r0 = bm * BM + wm * WR + (lane >> 4) * 4;
  const int c0 = bn * 128 + wn * 64 + (lane & 15);
#pragma unroll
  for (int i = 0; i < MI; i++) {
#pragma unroll
    for (int j = 0; j < 4; j++) {
      const int col = c0 + j * 16;
#pragma unroll
      for (int r = 0; r < 4; r++) {
        const int row = r0 + i * 16 + r;
        const float v = acc[i][j][r] * s;
        const size_t idx = (size_t)row * N + col;
        if (mode == EP_STORE) {
          outb[idx] = (bf16_t)v;
        } else if (mode == EP_BIAS_RES) {
          const float add = v + bias[col];
          if (fout) fout[idx] = resid[idx] + add;      // final-layer fused output
          else      resid[idx] += add;
        } else {  // EP_BIAS_GELU
          outb[idx] = (bf16_t)gelu_fast(v + bias[col]);
        }
      }
    }
  }
}

// ---------------- LayerNorm: one block per row; vectorized loads (G13) ----------------
template <typename TIN>
__global__ __launch_bounds__(256)
void ln_kern(const TIN* __restrict__ x, const float* __restrict__ g,
             const float* __restrict__ b, bf16_t* __restrict__ y, const int W)
{
  const int row = blockIdx.x;
  const int tid = threadIdx.x;
  const TIN* xr = x + (size_t)row * W;
  float s = 0.f, s2 = 0.f;
  if constexpr (sizeof(TIN) == 4) {
    const f32x4* xv = (const f32x4*)xr;
    for (int i = tid; i < W / 4; i += 256) {
      f32x4 v = xv[i];
#pragma unroll
      for (int e = 0; e < 4; e++) { s += v[e]; s2 += v[e] * v[e]; }
    }
  } else {
    const bf16x8* xv = (const bf16x8*)xr;
    for (int i = tid; i < W / 8; i += 256) {
      bf16x8 v = xv[i];
#pragma unroll
      for (int e = 0; e < 8; e++) { const float f = (float)v[e]; s += f; s2 += f * f; }
    }
  }
#pragma unroll
  for (int off = 32; off > 0; off >>= 1) {
    s  += __shfl_xor(s,  off, 64);
    s2 += __shfl_xor(s2, off, 64);
  }
  __shared__ float red[8];
  if ((tid & 63) == 0) { red[(tid >> 6) * 2] = s; red[(tid >> 6) * 2 + 1] = s2; }
  __syncthreads();
  const float ts  = red[0] + red[2] + red[4] + red[6];
  const float ts2 = red[1] + red[3] + red[5] + red[7];
  const float invW = 1.0f / (float)W;
  const float mean = ts * invW;
  const float var  = fmaxf(ts2 * invW - mean * mean, 0.f);
  const float rs   = rsqrtf(var + 1e-5f);
  bf16_t* yr = y + (size_t)row * W;
  const f32x4* gv = (const f32x4*)g;
  const f32x4* bv = (const f32x4*)b;
  if constexpr (sizeof(TIN) == 4) {
    const f32x4* xv = (const f32x4*)xr;
    bf16x4* yv = (bf16x4*)yr;
    for (int i = tid; i < W / 4; i += 256) {
      f32x4 v = xv[i], gg = gv[i], bb = bv[i];
      bf16x4 o;
#pragma unroll
      for (int e = 0; e < 4; e++) o[e] = (bf16_t)((v[e] - mean) * rs * gg[e] + bb[e]);
      yv[i] = o;
    }
  } else {
    const bf16x8* xv = (const bf16x8*)xr;
    bf16x8* yv = (bf16x8*)yr;
    for (int i = tid; i < W / 8; i += 256) {
      bf16x8 v = xv[i];
      f32x4 g0 = gv[2 * i], g1 = gv[2 * i + 1];
      f32x4 b0 = bv[2 * i], b1 = bv[2 * i + 1];
      bf16x8 o;
#pragma unroll
      for (int e = 0; e < 4; e++) o[e]     = (bf16_t)(((float)v[e]     - mean) * rs * g0[e] + b0[e]);
#pragma unroll
      for (int e = 0; e < 4; e++) o[e + 4] = (bf16_t)(((float)v[e + 4] - mean) * rs * g1[e] + b1[e]);
      yv[i] = o;
    }
  }
}

// ---------------- MFMA flash attention ----------------
// grid (NSEQ/64, NH, NB), 256 threads = 4 waves; T14 async-stage; Pw wave-private.
// Softmax in log2 domain; T13 defer-max (THR=8); lane-partial denom reduced once.
__global__ __launch_bounds__(256)
void attn_mfma(const bf16_t* __restrict__ qkv, bf16_t* __restrict__ o)
{
  __shared__ __align__(16) bf16_t Ks[64][72];      // K [kv][d], +8 pad
  __shared__ __align__(16) bf16_t Vt[64][72];      // V^T [d][kv], +8 pad
  __shared__ __align__(16) bf16_t Pw[4][16][72];   // per-wave P [q][kv], +8 pad
  const float SCL = 0.125f * 1.44269504088896f;    // scale * log2(e)
  const int tid  = threadIdx.x;
  const int lane = tid & 63;
  const int wave = tid >> 6;
  const int quad = lane >> 4;
  const int l15  = lane & 15;
  const int qb = blockIdx.x, hh = blockIdx.y, bb = blockIdx.z;
  const size_t tokbase = (size_t)bb * NSEQ;

  const int qrow = qb * 64 + wave * 16 + l15;
  bf16x8 qf[2];
  {
    const bf16_t* qp = qkv + (tokbase + qrow) * QKVW + hh * DH;
    qf[0] = *(const bf16x8*)(qp + quad * 8);
    qf[1] = *(const bf16x8*)(qp + 32 + quad * 8);
  }

  f32x4 Ot[4];
#pragma unroll
  for (int i = 0; i < 4; i++) Ot[i] = (f32x4){0.f, 0.f, 0.f, 0.f};
  float m2[4], lp[4];                // m in log2 units; lp = lane-partial denom
#pragma unroll
  for (int r = 0; r < 4; r++) { m2[r] = -1e30f; lp[r] = 0.f; }

  const int skv = tid & 63;
  const int sd  = (tid >> 6) * 16;

  bf16x8 k0, k1, v0, v1;
  {
    const bf16_t* kp = qkv + (tokbase + skv) * QKVW + INNERV + hh * DH + sd;
    k0 = *(const bf16x8*)kp;
    k1 = *(const bf16x8*)(kp + 8);
    v0 = *(const bf16x8*)(kp + INNERV);
    v1 = *(const bf16x8*)(kp + INNERV + 8);
  }

  for (int kt = 0; kt < NSEQ / 64; ++kt) {
    __syncthreads();
    *(bf16x8*)&Ks[skv][sd]     = k0;
    *(bf16x8*)&Ks[skv][sd + 8] = k1;
#pragma unroll
    for (int e = 0; e < 8; e++) { Vt[sd + e][skv] = v0[e]; Vt[sd + 8 + e][skv] = v1[e]; }
    __syncthreads();

    // issue next tile's loads NOW — in flight across the whole compute phase (T14)
    bf16x8 nk0 = k0, nk1 = k1, nv0 = v0, nv1 = v1;
    if (kt + 1 < NSEQ / 64) {
      const bf16_t* kp = qkv + (tokbase + (kt + 1) * 64 + skv) * QKVW + INNERV + hh * DH + sd;
      nk0 = *(const bf16x8*)kp;
      nk1 = *(const bf16x8*)(kp + 8);
      nv0 = *(const bf16x8*)(kp + INNERV);
      nv1 = *(const bf16x8*)(kp + INNERV + 8);
    }

    f32x4 st[4];
    __builtin_amdgcn_s_setprio(1);
#pragma unroll
    for (int nt = 0; nt < 4; nt++) {
      bf16x8 b0 = *(const bf16x8*)&Ks[nt * 16 + l15][quad * 8];
      bf16x8 b1 = *(const bf16x8*)&Ks[nt * 16 + l15][32 + quad * 8];
      f32x4 c = (f32x4){0.f, 0.f, 0.f, 0.f};
      c = __builtin_amdgcn_mfma_f32_16x16x32_bf16(qf[0], b0, c, 0, 0, 0);
      c = __builtin_amdgcn_mfma_f32_16x16x32_bf16(qf[1], b1, c, 0, 0, 0);
      st[nt] = c;
    }
    __builtin_amdgcn_s_setprio(0);

    float rmax2[4];
#pragma unroll
    for (int r = 0; r < 4; r++) {
      float v = fmaxf(fmaxf(st[0][r], st[1][r]), fmaxf(st[2][r], st[3][r]));
      v = fmaxf(v, __shfl_xor(v, 1, 64));
      v = fmaxf(v, __shfl_xor(v, 2, 64));
      v = fmaxf(v, __shfl_xor(v, 4, 64));
      v = fmaxf(v, __shfl_xor(v, 8, 64));
      rmax2[r] = v * SCL;
    }
    const bool ok = (rmax2[0] <= m2[0] + 8.f) && (rmax2[1] <= m2[1] + 8.f) &&
                    (rmax2[2] <= m2[2] + 8.f) && (rmax2[3] <= m2[3] + 8.f);
    if (!__all(ok)) {
#pragma unroll
      for (int r = 0; r < 4; r++) {
        const float mnew = fmaxf(m2[r], rmax2[r]);
        const float alpha = exp2f(m2[r] - mnew);
        m2[r] = mnew;
        lp[r] *= alpha;
#pragma unroll
        for (int dt = 0; dt < 4; dt++) Ot[dt][r] *= alpha;
      }
    }
#pragma unroll
    for (int nt = 0; nt < 4; nt++) {
#pragma unroll
      for (int r = 0; r < 4; r++) {
        const float p = exp2f(fmaf(st[nt][r], SCL, -m2[r]));
        lp[r] += p;
        Pw[wave][quad * 4 + r][nt * 16 + l15] = (bf16_t)p;
      }
    }

    asm volatile("s_waitcnt lgkmcnt(0)" ::: "memory");
    __builtin_amdgcn_sched_barrier(0);

    __builtin_amdgcn_s_setprio(1);
#pragma unroll
    for (int kk = 0; kk < 2; kk++) {
      bf16x8 pa = *(const bf16x8*)&Pw[wave][l15][kk * 32 + quad * 8];
#pragma unroll
      for (int dt = 0; dt < 4; dt++) {
        bf16x8 vb = *(const bf16x8*)&Vt[dt * 16 + l15][kk * 32 + quad * 8];
        Ot[dt] = __builtin_amdgcn_mfma_f32_16x16x32_bf16(pa, vb, Ot[dt], 0, 0, 0);
      }
    }
    __builtin_amdgcn_s_setprio(0);

    k0 = nk0; k1 = nk1; v0 = nv0; v1 = nv1;
  }

  float inv[4];
#pragma unroll
  for (int r = 0; r < 4; r++) {
    float v = lp[r];
    v += __shfl_xor(v, 1, 64);
    v += __shfl_xor(v, 2, 64);
    v += __shfl_xor(v, 4, 64);
    v += __shfl_xor(v, 8, 64);
    inv[r] = 1.0f / v;
  }
#pragma unroll
  for (int dt = 0; dt < 4; dt++) {
#pragma unroll
    for (int r = 0; r < 4; r++) {
      const int q = qb * 64 + wave * 16 + quad * 4 + r;
      const int d = dt * 16 + l15;
      o[(tokbase + q) * INNERV + hh * DH + d] = (bf16_t)(Ot[dt][r] * inv[r]);
    }
  }
}

// ---------------- ternary quant helpers (f32 weights in), batched x4 ----------------
__global__ __launch_bounds__(64)
void zero_kern(float* __restrict__ p)
{
  p[threadIdx.x] = 0.f;
}

__global__ __launch_bounds__(256)
void absmean4_kern(const float* __restrict__ w0, const float* __restrict__ w1,
                   const float* __restrict__ w2, const float* __restrict__ w3,
                   const long n0, const long n1, const long n2, const long n3,
                   float* __restrict__ acc)
{
  const int t = blockIdx.y;
  const float* w = (t == 0) ? w0 : (t == 1) ? w1 : (t == 2) ? w2 : w3;
  const long  n  = (t == 0) ? n0 : (t == 1) ? n1 : (t == 2) ? n2 : n3;
  const int tid = threadIdx.x;
  float s = 0.f;
  const size_t stride = (size_t)256 * gridDim.x * 4;
  for (size_t i = ((size_t)blockIdx.x * 256 + tid) * 4; i < (size_t)n; i += stride) {
    f32x4 v = *(const f32x4*)(w + i);
    s += fabsf(v[0]) + fabsf(v[1]) + fabsf(v[2]) + fabsf(v[3]);
  }
#pragma unroll
  for (int off = 32; off > 0; off >>= 1) s += __shfl_xor(s, off, 64);
  __shared__ float red[4];
  if ((tid & 63) == 0) red[tid >> 6] = s;
  __syncthreads();
  if (tid == 0) atomicAdd(&acc[t], red[0] + red[1] + red[2] + red[3]);
}

__global__ __launch_bounds__(256)
void quant4_kern(const float* __restrict__ w0, const float* __restrict__ w1,
                 const float* __restrict__ w2, const float* __restrict__ w3,
                 bf16_t* __restrict__ q0, bf16_t* __restrict__ q1,
                 bf16_t* __restrict__ q2, bf16_t* __restrict__ q3,
                 const int n40, const int n41, const int n42, const int n43,
                 const float* __restrict__ acc,
                 const float inv0, const float inv1, const float inv2, const float inv3)
{
  const int t = blockIdx.y;
  const float* w = (t == 0) ? w0 : (t == 1) ? w1 : (t == 2) ? w2 : w3;
  bf16_t*      q = (t == 0) ? q0 : (t == 1) ? q1 : (t == 2) ? q2 : q3;
  const int   n4 = (t == 0) ? n40 : (t == 1) ? n41 : (t == 2) ? n42 : n43;
  const float iv = (t == 0) ? inv0 : (t == 1) ? inv1 : (t == 2) ? inv2 : inv3;
  const int i = blockIdx.x * 256 + threadIdx.x;
  if (i >= n4) return;
  const float s = acc[t] * iv + 1e-8f;
  f32x4 v = ((const f32x4*)w)[i];
  bf16x4 o;
#pragma unroll
  for (int e = 0; e < 4; e++) {
    float qv = rintf(v[e] / s);  // round-half-even, matches jnp.round
    qv = fminf(1.f, fmaxf(-1.f, qv));
    o[e] = (bf16_t)qv;
  }
  ((bf16x4*)q)[i] = o;
}

__global__ __launch_bounds__(256)
void cast4_kern(const float* __restrict__ w0, const float* __restrict__ w1,
                const float* __restrict__ w2, const float* __restrict__ w3,
                bf16_t* __restrict__ q0, bf16_t* __restrict__ q1,
                bf16_t* __restrict__ q2, bf16_t* __restrict__ q3,
                const int n40, const int n41, const int n42, const int n43)
{
  const int t = blockIdx.y;
  const float* w = (t == 0) ? w0 : (t == 1) ? w1 : (t == 2) ? w2 : w3;
  bf16_t*      q = (t == 0) ? q0 : (t == 1) ? q1 : (t == 2) ? q2 : q3;
  const int   n4 = (t == 0) ? n40 : (t == 1) ? n41 : (t == 2) ? n42 : n43;
  const int i = blockIdx.x * 256 + threadIdx.x;
  if (i >= n4) return;
  f32x4 v = ((const f32x4*)w)[i];
  bf16x4 o;
#pragma unroll
  for (int e = 0; e < 4; e++) o[e] = (bf16_t)v[e];
  ((bf16x4*)q)[i] = o;
}

__global__ __launch_bounds__(256)
void copyf_kern(const float* __restrict__ in, float* __restrict__ out, const int n4)
{
  const int i = blockIdx.x * 256 + threadIdx.x;
  if (i < n4) ((f32x4*)out)[i] = ((const f32x4*)in)[i];
}

// ---------------- driver ----------------
extern "C" void kernel_launch(void* const* d_in, const int* in_sizes, int n_in,
                              void* d_out, int out_size, void* d_ws, size_t ws_size,
                              hipStream_t stream)
{
  const float* x     = (const float*)d_in[0];
  const float* ln1_g = (const float*)d_in[1];
  const float* ln1_b = (const float*)d_in[2];
  const float* Wqkv  = (const float*)d_in[3];
  const float* ln2_g = (const float*)d_in[4];
  const float* ln2_b = (const float*)d_in[5];
  const float* Wo    = (const float*)d_in[6];
  const float* bo    = (const float*)d_in[7];
  const float* fg1   = (const float*)d_in[8];
  const float* fb1   = (const float*)d_in[9];
  const float* W1    = (const float*)d_in[10];
  const float* b1    = (const float*)d_in[11];
  const float* fg2   = (const float*)d_in[12];
  const float* fb2   = (const float*)d_in[13];
  const float* W2    = (const float*)d_in[14];
  const float* b2    = (const float*)d_in[15];

  char* ws = (char*)d_ws;
  size_t off = 0;
  float*  sacc  = (float*)(ws + off);  off += 256;                         // scale sums; [63] stays 0
  float*  h     = (float*)(ws + off);  off += (size_t)TOKENS * DIMV * 4;   // 25.2 MB residual stream
  bf16_t* bigA  = (bf16_t*)(ws + off); off += (size_t)TOKENS * MLPW * 2;   // 50.3 MB LN outs / attn out
  bf16_t* bigB  = (bf16_t*)(ws + off); off += (size_t)TOKENS * MLPW * 2;   // 50.3 MB qkv / gelu out
  bf16_t* q_qkv = (bf16_t*)(ws + off); off += (size_t)QKVW * DIMV * 2;
  bf16_t* q_o   = (bf16_t*)(ws + off); off += (size_t)DIMV * INNERV * 2;
  bf16_t* q_1   = (bf16_t*)(ws + off); off += (size_t)MLPW * DIMV * 2;
  bf16_t* q_2   = (bf16_t*)(ws + off); off += (size_t)DIMV * MLPW * 2;     // total ~140 MB

  bf16_t* obuf   = bigA;                              // attn out (12.6 MB)
  bf16_t* ln2out = bigA + (size_t)TOKENS * INNERV;    // LN2 out

  zero_kern<<<1, 64, 0, stream>>>(sacc);
  copyf_kern<<<TOKENS * DIMV / 4 / 256, 256, 0, stream>>>(x, h, TOKENS * DIMV / 4);

  for (int lyr = 0; lyr < 6; ++lyr) {
    const float* wqkv_l = Wqkv + (size_t)lyr * QKVW * DIMV;
    const float* wo_l   = Wo   + (size_t)lyr * DIMV * INNERV;
    const float* w1_l   = W1   + (size_t)lyr * MLPW * DIMV;
    const float* w2_l   = W2   + (size_t)lyr * DIMV * MLPW;
    const float *sq, *so, *s1, *s2p;
    float iq, io, i1, i2, bq, bo2, bb1v, bb2v;
    if (lyr < 5) {
      absmean4_kern<<<dim3(64, 4), 256, 0, stream>>>(
          wqkv_l, wo_l, w1_l, w2_l,
          (long)QKVW * DIMV, (long)DIMV * INNERV, (long)MLPW * DIMV, (long)DIMV * MLPW,
          &sacc[lyr * 4]);
      quant4_kern<<<dim3(MLPW * DIMV / 1024, 4), 256, 0, stream>>>(
          wqkv_l, wo_l, w1_l, w2_l, q_qkv, q_o, q_1, q_2,
          QKVW * DIMV / 4, DIMV * INNERV / 4, MLPW * DIMV / 4, DIMV * MLPW / 4,
          &sacc[lyr * 4],
          1.0f / (QKVW * DIMV), 1.0f / (DIMV * INNERV), 1.0f / (MLPW * DIMV), 1.0f / (DIMV * MLPW));
      sq = &sacc[lyr * 4 + 0]; iq = 1.0f / (QKVW * DIMV); bq = 1e-8f;
      so = &sacc[lyr * 4 + 1]; io = 1.0f / (DIMV * INNERV); bo2 = 1e-8f;
      s1 = &sacc[lyr * 4 + 2]; i1 = 1.0f / (MLPW * DIMV); bb1v = 1e-8f;
      s2p = &sacc[lyr * 4 + 3]; i2 = 1.0f / (DIMV * MLPW); bb2v = 1e-8f;
    } else {
      cast4_kern<<<dim3(MLPW * DIMV / 1024, 4), 256, 0, stream>>>(
          wqkv_l, wo_l, w1_l, w2_l, q_qkv, q_o, q_1, q_2,
          QKVW * DIMV / 4, DIMV * INNERV / 4, MLPW * DIMV / 4, DIMV * MLPW / 4);
      sq = so = s1 = s2p = &sacc[63];  // contains 0
      iq = io = i1 = i2 = 0.f;
      bq = bo2 = bb1v = bb2v = 1.0f;   // s = 0*0 + 1 = 1
    }

    // attention sub-block
    ln_kern<float><<<TOKENS, 256, 0, stream>>>(h, ln1_g + lyr * DIMV, ln1_b + lyr * DIMV, bigA, DIMV);
    gemm_nt<128><<<dim3(64, QKVW / 128), 256, 0, stream>>>(bigA, q_qkv, DIMV, QKVW, EP_STORE, sq, iq, bq, nullptr, nullptr, bigB, nullptr);
    attn_mfma<<<dim3(NSEQ / 64, NH, NB), 256, 0, stream>>>(bigB, obuf);
    ln_kern<bf16_t><<<TOKENS, 256, 0, stream>>>(obuf, ln2_g + lyr * INNERV, ln2_b + lyr * INNERV, ln2out, INNERV);
    gemm_nt<64><<<dim3(TOKENS / 64, DIMV / 128), 256, 0, stream>>>(ln2out, q_o, INNERV, DIMV, EP_BIAS_RES, so, io, bo2, bo + lyr * DIMV, h, nullptr, nullptr);
    // FF sub-block
    ln_kern<float><<<TOKENS, 256, 0, stream>>>(h, fg1 + lyr * DIMV, fb1 + lyr * DIMV, bigA, DIMV);
    gemm_nt<128><<<dim3(64, MLPW / 128), 256, 0, stream>>>(bigA, q_1, DIMV, MLPW, EP_BIAS_GELU, s1, i1, bb1v, b1 + lyr * MLPW, nullptr, bigB, nullptr);
    ln_kern<bf16_t><<<TOKENS, 256, 0, stream>>>(bigB, fg2 + lyr * MLPW, fb2 + lyr * MLPW, bigA, MLPW);
    // last layer: fuse the residual add + output write (h + v + bias -> d_out)
    gemm_nt<64><<<dim3(TOKENS / 64, DIMV / 128), 256, 0, stream>>>(bigA, q_2, MLPW, DIMV, EP_BIAS_RES, s2p, i2, bb2v, b2 + lyr * DIMV, h, nullptr,
                                                                   (lyr == 5) ? (float*)d_out : nullptr);
  }
}